// Round 8
// baseline (354.169 us; speedup 1.0000x reference)
//
#include <hip/hip_runtime.h>
#include <hip/hip_fp16.h>

// Problem constants (from reference)
#define NN  100000   // nodes
#define FIN 128      // in features
#define HID 256      // hidden
#define NE  600000   // edges
#define FEPS 1e-12f

// ---------------------------------------------------------------------------
// Workspace layout (unchanged sizes):
//  Path A (~82.3 MB): Bfh|Bfl[65536]h frag-order (=256KB) | xh[NN*FIN]h |
//                     aggH|aggL[NN*128]h | cnt|cur|off|col | g|r | bsum
// Evidence log:
//  - R5: bf16 FEATURES fail precision; fp16 OK (absmax 0.0156 vs thr 0.0327).
//  - R13: SPLIT WINS: barrier-free gather; gemm exposed.
//  - R16: MFMA 3-product fp16 emulation: 245->147.8 us.
//  - R17: frag-contiguous B + full unroll, bounds(512,4): 73.1 us, Occ 34%.
//  - R19: bounds(512,8) cap-64 => 92MB scratch spill, 96 us (Occ 62%).
//  - R20: bounds(512,4): no spill, 73.8 us, Occ 34.6%.
//  - R21: bounds(512,6): Occ 51.7% but dur FLAT 74 => occupancy NOT the
//    lever; + issue-early xv spilled (WRITE 36MB).
//  - R22: M=128 acc[8][2]=64reg: spilled AGAIN (WRITE 20MB, conflicts 2x,
//    grid 782) => 105.6 us. CONSTRAINT CONFIRMED: acc must stay <=32 regs
//    to leave hoist headroom under the 128 cap.
//  - Floors: MFMA ~5us wall, B-L2 ~5us (dup-1), HBM ~8us. 74us = latency/
//    barrier overhead, insensitive to occupancy.
//  - R23 (this): duplication-1 with SMALL acc: 1024 thr / 16 waves, M=64;
//    wave w = ONE 16-j group x all 4 Mtiles => acc[4]=16 VGPRs; B per
//    block = 256KB exactly (L2 traffic 800->400MB); 2 B loads feed 12
//    MFMAs per s-step with ~80 free VGPRs for cross-step B hoisting.
//    Single K=256 phase, 4 LDS arrays (AggH|AggL|XH|XL = 64KB): 3 sync
//    points instead of 5. bounds(1024,4) cap 128 (proven-safe regime).
//    Numerics identical. Predicted: WRITE ~1.7MB (tripwire), VGPR 64-100,
//    gemm 74 -> 45-58 us, total ~240-255 us, absmax exactly 0.015625.
// ---------------------------------------------------------------------------

typedef _Float16 f16x8 __attribute__((ext_vector_type(8)));
typedef float    f32x4 __attribute__((ext_vector_type(4)));

__device__ __forceinline__ int clampN(int v) {
    return ((unsigned)v < (unsigned)NN) ? v : 0;
}
// int64 vs int32 edge_index: little-endian int64 (<2^31) => odd words all 0.
__device__ __forceinline__ int detect4(const int* ei) {
    return ((ei[1] | ei[3] | ei[5] | ei[7]) == 0) ? 1 : 0;
}
__device__ __forceinline__ int ld_src(const int* ei, int e, int f) {
    return f ? ei[2 * e] : ei[e];
}
__device__ __forceinline__ int ld_dst(const int* ei, int e, int f) {
    return f ? ei[2 * (NE + e)] : ei[NE + e];
}

__device__ __forceinline__ unsigned packh2(__half a, __half b) {
    return __builtin_bit_cast(unsigned, __halves2half2(a, b));
}

// Fragment-order index for weight element (j, k):
// [kchunk = k>>5][jgroup = j>>4][lane = ((k>>3)&3)*16 + (j&15)][e = k&7]
__device__ __forceinline__ size_t fragIdx(int j, int k) {
    return ((size_t)((k >> 5) * 16 + (j >> 4)) * 64 +
            (size_t)(((k >> 3) & 3) * 16 + (j & 15))) * 8 + (k & 7);
}

// ---------------------------------------------------------------------------
// Setup (fused): blocks [0,256) split weights to fp16 hi/lo in FRAG layout;
// [256,256+ncv) x->fp16; [256+ncv, ...) in-degree count (cnt pre-zeroed).
// ---------------------------------------------------------------------------
__global__ __launch_bounds__(256) void setup_kernel(
    const int* __restrict__ ei,
    const float* __restrict__ x,
    const float* __restrict__ W1l, const float* __restrict__ W1r,
    __half* __restrict__ Bfh, __half* __restrict__ Bfl,
    __half* __restrict__ xh,
    int* __restrict__ cnt, int ncv)
{
    int b = blockIdx.x;
    int t = threadIdx.x;
    if (b < 256) {
        int j = b, k2 = t;   // row j of [W1l | W1r], contiguous k
        float v = (k2 < FIN) ? W1l[(size_t)j * FIN + k2]
                             : W1r[(size_t)j * FIN + (k2 - FIN)];
        __half h  = __float2half_rn(v);
        __half lo = __float2half_rn(v - __half2float(h));
        size_t fi = fragIdx(j, k2);
        Bfh[fi] = h;
        Bfl[fi] = lo;
    } else if (b < 256 + ncv) {
        int idx = (b - 256) * 256 + t;           // 8-float group
        if (idx < NN * FIN / 8) {
            const float4* px = (const float4*)(x + (size_t)idx * 8);
            float4 v0 = px[0], v1 = px[1];
            uint4 u;
            u.x = packh2(__float2half_rn(v0.x), __float2half_rn(v0.y));
            u.y = packh2(__float2half_rn(v0.z), __float2half_rn(v0.w));
            u.z = packh2(__float2half_rn(v1.x), __float2half_rn(v1.y));
            u.w = packh2(__float2half_rn(v1.z), __float2half_rn(v1.w));
            ((uint4*)xh)[idx] = u;
        }
    } else {
        int e = (b - 256 - ncv) * 256 + t;
        if (e < NE) {
            int f = detect4(ei);
            atomicAdd(cnt + clampN(ld_dst(ei, e, f)), 1);
        }
    }
}

// 3-phase parallel exclusive scan of cnt[NN] -> off[NN+1]
__global__ __launch_bounds__(1024) void scan_a_kernel(
    const int* __restrict__ cnt, int* __restrict__ off, int* __restrict__ bsum)
{
    __shared__ int sm[1024];
    int t = threadIdx.x;
    int idx = blockIdx.x * 1024 + t;
    int v = (idx < NN) ? cnt[idx] : 0;
    sm[t] = v;
    __syncthreads();
    for (int d = 1; d < 1024; d <<= 1) {
        int w = (t >= d) ? sm[t - d] : 0;
        __syncthreads();
        sm[t] += w;
        __syncthreads();
    }
    if (idx < NN) off[idx] = sm[t] - v;
    if (t == 1023) bsum[blockIdx.x] = sm[1023];
}
__global__ __launch_bounds__(128) void scan_b_kernel(
    int* __restrict__ bsum, int* __restrict__ off, int nblocks)
{
    __shared__ int sm[128];
    int t = threadIdx.x;
    int v = (t < nblocks) ? bsum[t] : 0;
    sm[t] = v;
    __syncthreads();
    for (int d = 1; d < 128; d <<= 1) {
        int w = (t >= d) ? sm[t - d] : 0;
        __syncthreads();
        sm[t] += w;
        __syncthreads();
    }
    if (t < nblocks) bsum[t] = sm[t] - v;
    if (t == 0) off[NN] = NE;
}
__global__ __launch_bounds__(1024) void scan_c_kernel(
    const int* __restrict__ bsum, int* __restrict__ off)
{
    int idx = blockIdx.x * 1024 + threadIdx.x;
    if (idx < NN) off[idx] += bsum[blockIdx.x];
}

// place src ids into CSR slots
__global__ __launch_bounds__(256) void fill_kernel(
    const int* __restrict__ ei,
    const int* __restrict__ off, int* __restrict__ cur, int* __restrict__ col)
{
    int e = blockIdx.x * 256 + threadIdx.x;
    if (e >= NE) return;
    int f = detect4(ei);
    int src = clampN(ld_src(ei, e, f));
    int dst = clampN(ld_dst(ei, e, f));
    int p = atomicAdd(cur + dst, 1);
    col[off[dst] + p] = src;
}

// ---------------------------------------------------------------------------
// Path A, stage 1: barrier-free gather. 1 thread per (node, 16B fp16 chunk);
// 4-wide independent-load loop. Mean split to fp16 hi/lo and written
// PRE-SWIZZLED: chunk ft stored at position ft^(n&7) within the row, so the
// GEMM's staging is a pure linear copy. (Numerics identical to fp32 agg.)
// ---------------------------------------------------------------------------
__global__ __launch_bounds__(256) void gather_kernel(
    const int* __restrict__ off, const int* __restrict__ col,
    const __half* __restrict__ xh,
    __half* __restrict__ aggH, __half* __restrict__ aggL)
{
    int idx = blockIdx.x * 256 + threadIdx.x;
    if (idx >= NN * 16) return;
    int n     = idx >> 4;
    int ft    = idx & 15;
    int fbase = ft * 8;

    float a[8];
#pragma unroll
    for (int i = 0; i < 8; ++i) a[i] = 0.0f;

    int s0 = off[n], s1 = off[n + 1];
    int i = s0;
    for (; i + 3 < s1; i += 4) {            // 4 independent 16B loads
        int c0 = clampN(col[i]);
        int c1 = clampN(col[i + 1]);
        int c2 = clampN(col[i + 2]);
        int c3 = clampN(col[i + 3]);
        uint4 v0 = *(const uint4*)(xh + (size_t)c0 * FIN + fbase);
        uint4 v1 = *(const uint4*)(xh + (size_t)c1 * FIN + fbase);
        uint4 v2 = *(const uint4*)(xh + (size_t)c2 * FIN + fbase);
        uint4 v3 = *(const uint4*)(xh + (size_t)c3 * FIN + fbase);
#pragma unroll
        for (int u = 0; u < 4; ++u) {
            float2 f0 = __half22float2(__builtin_bit_cast(__half2, (&v0.x)[u]));
            float2 f1 = __half22float2(__builtin_bit_cast(__half2, (&v1.x)[u]));
            float2 f2 = __half22float2(__builtin_bit_cast(__half2, (&v2.x)[u]));
            float2 f3 = __half22float2(__builtin_bit_cast(__half2, (&v3.x)[u]));
            a[2 * u]     += (f0.x + f1.x) + (f2.x + f3.x);
            a[2 * u + 1] += (f0.y + f1.y) + (f2.y + f3.y);
        }
    }
    for (; i < s1; ++i) {
        int c0 = clampN(col[i]);
        uint4 v0 = *(const uint4*)(xh + (size_t)c0 * FIN + fbase);
#pragma unroll
        for (int u = 0; u < 4; ++u) {
            float2 f0 = __half22float2(__builtin_bit_cast(__half2, (&v0.x)[u]));
            a[2 * u]     += f0.x;
            a[2 * u + 1] += f0.y;
        }
    }
    float ic = 1.0f / fmaxf((float)(s1 - s0), 1.0f);
    __half h[8], lo[8];
#pragma unroll
    for (int k = 0; k < 8; ++k) {
        float v = a[k] * ic;
        h[k]  = __float2half_rn(v);
        lo[k] = __float2half_rn(v - __half2float(h[k]));
    }
    uint4 uh, ul;
    uh.x = packh2(h[0], h[1]);  uh.y = packh2(h[2], h[3]);
    uh.z = packh2(h[4], h[5]);  uh.w = packh2(h[6], h[7]);
    ul.x = packh2(lo[0], lo[1]); ul.y = packh2(lo[2], lo[3]);
    ul.z = packh2(lo[4], lo[5]); ul.w = packh2(lo[6], lo[7]);
    size_t rowb = (size_t)n * 128 + (size_t)((ft ^ (n & 7)) << 3);
    *(uint4*)(aggH + rowb) = uh;
    *(uint4*)(aggL + rowb) = ul;
}

// fp32 -> fp16 hi/lo split of 4 floats, stored as uint2 pairs at LDS addr.
__device__ __forceinline__ void splitStore4(
    __half* Ah, __half* Al, int addr, float4 v)
{
    __half h0 = __float2half_rn(v.x), h1 = __float2half_rn(v.y);
    __half h2 = __float2half_rn(v.z), h3 = __float2half_rn(v.w);
    __half l0 = __float2half_rn(v.x - __half2float(h0));
    __half l1 = __float2half_rn(v.y - __half2float(h1));
    __half l2 = __float2half_rn(v.z - __half2float(h2));
    __half l3 = __float2half_rn(v.w - __half2float(h3));
    uint2 uh, ul;
    uh.x = packh2(h0, h1);  uh.y = packh2(h2, h3);
    ul.x = packh2(l0, l1);  ul.y = packh2(l2, l3);
    *(uint2*)(Ah + addr) = uh;
    *(uint2*)(Al + addr) = ul;
}

// ---------------------------------------------------------------------------
// Path A, stage 2: MFMA GEMM, exact fp32 emulation, single K=256 phase,
// DUPLICATION-1 B. Block: 1024 thr (16 waves) = 64 nodes x 256 j.
// Wave w: jgroup w (16 j), ALL 4 Mtiles => acc[4] = 16 VGPRs (R22's 64-reg
// acc spilled; small acc leaves ~80 VGPRs for B hoisting). Each B fragment
// read EXACTLY ONCE per block: 256KB/block, 400MB total (half of R20).
// LDS: AggH|AggL|XH|XL = 4 x 16KB = 64KB, one staging barrier (3 sync
// points vs R20's 5). bounds(1024,4): cap 128 VGPR (proven-safe regime).
// Per s-step (K=32): 2 B loads feed 12 MFMAs (4 Mtiles x 3-term emulation
// Ah*Bh + Al*Bh + Ah*Bl, fp32 acc — exact).
// C layout (m89-verified): col=lane&15 (j), row=(lane>>4)*4+reg (node).
// ---------------------------------------------------------------------------
__global__ __launch_bounds__(1024, 4) void gemm_mfma_kernel(
    const __half* __restrict__ aggH, const __half* __restrict__ aggL,
    const float* __restrict__ x,
    const __half* __restrict__ Bfh, const __half* __restrict__ Bfl,
    const float* __restrict__ b1,
    const float* __restrict__ W2l, const float* __restrict__ W2r,
    float* __restrict__ g, float* __restrict__ r)
{
    __shared__ __align__(16) __half AS[4 * 64 * 128];   // 64 KB
    __half* AggHs = AS;
    __half* AggLs = AS + 64 * 128;
    __half* XHs   = AS + 2 * 64 * 128;
    __half* XLs   = AS + 3 * 64 * 128;

    const int t  = threadIdx.x;
    const int nb = blockIdx.x * 64;

    // ---- stage: agg linear copy (pre-swizzled; 1024 chunks per array).
    //      Tail blocks read past aggH row NN into adjacent ws (safe:
    //      garbage feeds only discarded rows; row-independent MFMA). ----
    {
        const uint4* gh = (const uint4*)(aggH + (size_t)nb * 128);
        const uint4* gl = (const uint4*)(aggL + (size_t)nb * 128);
        ((uint4*)AggHs)[t] = gh[t];
        ((uint4*)AggLs)[t] = gl[t];
    }
    // ---- stage: x fp32 -> hi/lo split, swizzled ----
    {
        const float4* xF = (const float4*)x;
        const float4 z4 = make_float4(0.f, 0.f, 0.f, 0.f);
#pragma unroll
        for (int i = 0; i < 2; ++i) {
            int idx   = i * 1024 + t;       // 0..2047 = 64 rows x 32 f4
            int n_loc = idx >> 5;
            int kq    = idx & 31;
            int n     = nb + n_loc;
            float4 v  = (n < NN) ? xF[(size_t)n * 32 + kq] : z4;
            int addr  = n_loc * 128 + ((((kq >> 1) ^ (n_loc & 7)) << 3) | ((kq & 1) << 2));
            splitStore4(XHs, XLs, addr, v);
        }
    }
    __syncthreads();

    const int l   = t & 63;
    const int w   = t >> 6;            // wave 0..15 = jgroup
    const int ln  = l & 15;
    const int kg  = l >> 4;            // 0..3
    const int r7  = ln & 7;            // Mtile bases are 0 mod 8

    f32x4 acc[4];
#pragma unroll
    for (int mt = 0; mt < 4; ++mt)
        acc[mt] = (f32x4){0.f, 0.f, 0.f, 0.f};

#pragma unroll
    for (int s = 0; s < 8; ++s) {      // K-step of 32: B kchunk s
        const size_t bo = (((size_t)s * 16 + w) * 64 + l) * 8;
        f16x8 bh = *reinterpret_cast<const f16x8*>(Bfh + bo);
        f16x8 bl = *reinterpret_cast<const f16x8*>(Bfl + bo);
        const int chunk = s * 4 + kg;  // 0..31 (8 halves each)
        const __half* AH = (s < 4) ? AggHs : XHs;
        const __half* AL = (s < 4) ? AggLs : XLs;
        const int sc = (s < 4) ? chunk : (chunk - 16);
        const int sl = (sc ^ r7) << 3;
#pragma unroll
        for (int mt = 0; mt < 4; ++mt) {
            const int base = (mt * 16 + ln) * 128 + sl;
            f16x8 ah = *reinterpret_cast<const f16x8*>(AH + base);
            f16x8 al = *reinterpret_cast<const f16x8*>(AL + base);
            acc[mt] = __builtin_amdgcn_mfma_f32_16x16x32_f16(ah, bh, acc[mt], 0, 0, 0);
            acc[mt] = __builtin_amdgcn_mfma_f32_16x16x32_f16(al, bh, acc[mt], 0, 0, 0);
            acc[mt] = __builtin_amdgcn_mfma_f32_16x16x32_f16(ah, bl, acc[mt], 0, 0, 0);
        }
    }

    // ---- epilogue: per-lane partials (1 j per lane), 16-lane shuffle
    //      reduce over this wave's 16 j, LDS-combine the 16 jgroups. ----
    const int j = w * 16 + ln;
    const float b1v  = b1[j];
    const float wl0v = W2l[j], wl1v = W2l[HID + j];
    const float wr0v = W2r[j], wr1v = W2r[HID + j];

    __syncthreads();                    // LDS reads done; overlay ok
    float* red = (float*)AS;            // [16 jgroup][64 node][5] = 20 KB
#pragma unroll
    for (int mt = 0; mt < 4; ++mt) {
#pragma unroll
        for (int rg = 0; rg < 4; ++rg) {
            float oo = acc[mt][rg] + b1v;
            float s_ = oo * oo;
            float pp = fmaxf(oo, 0.f);   // relu(o/D) = relu(o)/D
            float G0 = pp * wl0v;
            float G1 = pp * wl1v;
            float R0 = pp * wr0v;
            float R1 = pp * wr1v;
#pragma unroll
            for (int m = 1; m < 16; m <<= 1) {
                s_ += __shfl_xor(s_, m);
                G0 += __shfl_xor(G0, m);
                G1 += __shfl_xor(G1, m);
                R0 += __shfl_xor(R0, m);
                R1 += __shfl_xor(R1, m);
            }
            if (ln == 0) {
                int n_loc = mt * 16 + kg * 4 + rg;
                float* pp_ = red + ((size_t)w * 64 + n_loc) * 5;
                pp_[0] = s_; pp_[1] = G0; pp_[2] = G1; pp_[3] = R0; pp_[4] = R1;
            }
        }
    }
    __syncthreads();

    if (t < 64) {
        int n = nb + t;
        if (n < NN) {
            float s = 0.f, G0 = 0.f, G1 = 0.f, R0 = 0.f, R1 = 0.f;
#pragma unroll
            for (int jg = 0; jg < 16; ++jg) {
                const float* pp = red + ((size_t)jg * 64 + t) * 5;
                s += pp[0]; G0 += pp[1]; G1 += pp[2]; R0 += pp[3]; R1 += pp[4];
            }
            float inv = 1.0f / fmaxf(sqrtf(s), FEPS);
            g[2 * (size_t)n]     = G0 * inv;
            g[2 * (size_t)n + 1] = G1 * inv;
            r[2 * (size_t)n]     = R0 * inv;
            r[2 * (size_t)n + 1] = R1 * inv;
        }
    }
}

// ---------------------------------------------------------------------------
// Shared phase-B + epilogue body (FALLBACK paths only; weights reconstructed
// from fp16 hi+lo in frag layout, error ~2^-22 rel). Never runs on this
// harness (ws_size >= needA proven).
// ---------------------------------------------------------------------------
__device__ __forceinline__ void phaseB_epilogue(
    float* smem_f, int t, int l, int nb,
    const __half* __restrict__ Bfh, const __half* __restrict__ Bfl,
    const float* __restrict__ b1,
    const float* __restrict__ W2l, const float* __restrict__ W2r,
    float* __restrict__ g, float* __restrict__ r)
{
    const int w  = __builtin_amdgcn_readfirstlane(t >> 6);  // 0..15
    const int jb = w * 16;

    float o[16];
#pragma unroll
    for (int i = 0; i < 16; ++i) o[i] = 0.0f;

#pragma unroll 1
    for (int k2 = 0; k2 < 2 * FIN; k2 += 4) {
        const int nc = l ^ ((k2 >> 3) & 31);
        float av0 = smem_f[(k2 + 0) * 64 + nc];
        float av1 = smem_f[(k2 + 1) * 64 + nc];
        float av2 = smem_f[(k2 + 2) * 64 + nc];
        float av3 = smem_f[(k2 + 3) * 64 + nc];
#pragma unroll
        for (int i = 0; i < 16; ++i) {
            const size_t fb = ((size_t)((k2 >> 5) * 16 + ((jb + i) >> 4)) * 64 +
                               (size_t)(((k2 >> 3) & 3) * 16 + ((jb + i) & 15))) * 8 +
                              (k2 & 7);
            const __half* ph = Bfh + fb;
            const __half* pl = Bfl + fb;
            float oi = o[i];
            oi = fmaf(av0, __half2float(ph[0]) + __half2float(pl[0]), oi);
            oi = fmaf(av1, __half2float(ph[1]) + __half2float(pl[1]), oi);
            oi = fmaf(av2, __half2float(ph[2]) + __half2float(pl[2]), oi);
            oi = fmaf(av3, __half2float(ph[3]) + __half2float(pl[3]), oi);
            o[i] = oi;
        }
    }

    float sq = 0.f, g0 = 0.f, g1 = 0.f, r0 = 0.f, r1 = 0.f;
    const float* b1w  = b1  + jb;
    const float* w2la = W2l + jb;
    const float* w2lb = W2l + HID + jb;
    const float* w2ra = W2r + jb;
    const float* w2rb = W2r + HID + jb;
#pragma unroll
    for (int i = 0; i < 16; ++i) {
        float oo = o[i] + b1w[i];
        sq = fmaf(oo, oo, sq);
        float p = fmaxf(oo, 0.0f);
        g0 = fmaf(p, w2la[i], g0);
        g1 = fmaf(p, w2lb[i], g1);
        r0 = fmaf(p, w2ra[i], r0);
        r1 = fmaf(p, w2rb[i], r1);
    }

    __syncthreads();                          // tile dead; reuse as overlay
    smem_f[0 * 1024 + t] = sq;
    smem_f[1 * 1024 + t] = g0;
    smem_f[2 * 1024 + t] = g1;
    smem_f[3 * 1024 + t] = r0;
    smem_f[4 * 1024 + t] = r1;
    __syncthreads();

    if (t < 64) {
        int n2 = nb + t;
        float sqs = 0.f, G0 = 0.f, G1 = 0.f, R0 = 0.f, R1 = 0.f;
#pragma unroll
        for (int ww = 0; ww < 16; ++ww) {
            sqs += smem_f[0 * 1024 + ww * 64 + t];
            G0  += smem_f[1 * 1024 + ww * 64 + t];
            G1  += smem_f[2 * 1024 + ww * 64 + t];
            R0  += smem_f[3 * 1024 + ww * 64 + t];
            R1  += smem_f[4 * 1024 + ww * 64 + t];
        }
        float inv = 1.0f / fmaxf(sqrtf(sqs), FEPS);
        if (n2 < NN) {
            g[2 * (size_t)n2]     = G0 * inv;
            g[2 * (size_t)n2 + 1] = G1 * inv;
            r[2 * (size_t)n2]     = R0 * inv;
            r[2 * (size_t)n2 + 1] = R1 * inv;
        }
    }
}

// ---------------------------------------------------------------------------
// Paths B/C: fused layer-1 (B = fp16 gather, C = fp32). Fallback only.
// ---------------------------------------------------------------------------
template <bool HALFX>
__global__ __launch_bounds__(1024, 8) void layer1_kernel(
    const int* __restrict__ off, const int* __restrict__ col,
    const float* __restrict__ x, const __half* __restrict__ xh,
    const __half* __restrict__ Bfh, const __half* __restrict__ Bfl,
    const float* __restrict__ b1,
    const float* __restrict__ W2l, const float* __restrict__ W2r,
    float* __restrict__ g, float* __restrict__ r)
{
    __shared__ float smem_f[256 * 64];

    const int t  = threadIdx.x;
    const int nb = blockIdx.x * 64;
    const int l  = t & 63;

    {
        const int n_loc = t >> 4;
        const int ft    = t & 15;
        const int fbase = ft * 8;
        const int n     = nb + n_loc;
        const bool valid = (n < NN);

        float a[8];
#pragma unroll
        for (int i = 0; i < 8; ++i) a[i] = 0.0f;

        int s0 = 0, s1 = 0;
        if (valid) { s0 = off[n]; s1 = off[n + 1]; }

        int i = s0;
        if (HALFX) {
            for (; i + 3 < s1; i += 4) {
                int c0 = clampN(col[i]);
                int c1 = clampN(col[i + 1]);
                int c2 = clampN(col[i + 2]);
                int c3 = clampN(col[i + 3]);
                uint4 v0 = *(const uint4*)(xh + (size_t)c0 * FIN + fbase);
                uint4 v1 = *(const uint4*)(xh + (size_t)c1 * FIN + fbase);
                uint4 v2 = *(const uint4*)(xh + (size_t)c2 * FIN + fbase);
                uint4 v3 = *(const uint4*)(xh + (size_t)c3 * FIN + fbase);
#pragma unroll
                for (int u = 0; u < 4; ++u) {
                    float2 f0 = __half22float2(__builtin_bit_cast(__half2, (&v0.x)[u]));
                    float2 f1 = __half22float2(__builtin_bit_cast(__half2, (&v1.x)[u]));
                    float2 f2 = __half22float2(__builtin_bit_cast(__half2, (&v2.x)[u]));
                    float2 f3 = __half22float2(__builtin_bit_cast(__half2, (&v3.x)[u]));
                    a[2 * u]     += (f0.x + f1.x) + (f2.x + f3.x);
                    a[2 * u + 1] += (f0.y + f1.y) + (f2.y + f3.y);
                }
            }
            for (; i < s1; ++i) {
                int c0 = clampN(col[i]);
                uint4 v0 = *(const uint4*)(xh + (size_t)c0 * FIN + fbase);
#pragma unroll
                for (int u = 0; u < 4; ++u) {
                    float2 f0 = __half22float2(__builtin_bit_cast(__half2, (&v0.x)[u]));
                    a[2 * u]     += f0.x;
                    a[2 * u + 1] += f0.y;
                }
            }
        } else {
            for (; i < s1; ++i) {
                int c0 = clampN(col[i]);
                const float4* p0 = (const float4*)(x + (size_t)c0 * FIN + fbase);
                float4 v00 = p0[0], v01 = p0[1];
                a[0] += v00.x; a[1] += v00.y; a[2] += v00.z; a[3] += v00.w;
                a[4] += v01.x; a[5] += v01.y; a[6] += v01.z; a[7] += v01.w;
            }
        }
        float ic = 1.0f / fmaxf((float)(s1 - s0), 1.0f);
#pragma unroll
        for (int k = 0; k < 8; ++k) {
            int f = fbase + k;
            smem_f[f * 64 + (n_loc ^ ((f >> 3) & 31))] = a[k] * ic;
        }
        const float4* sp = (const float4*)(x + (size_t)(valid ? n : 0) * FIN + fbase);
        float4 s0v = valid ? sp[0] : make_float4(0.f, 0.f, 0.f, 0.f);
        float4 s1v = valid ? sp[1] : make_float4(0.f, 0.f, 0.f, 0.f);
        float sv[8] = {s0v.x, s0v.y, s0v.z, s0v.w, s1v.x, s1v.y, s1v.z, s1v.w};
#pragma unroll
        for (int k = 0; k < 8; ++k) {
            int f = FIN + fbase + k;
            smem_f[f * 64 + (n_loc ^ ((f >> 3) & 31))] = sv[k];
        }
    }
    __syncthreads();

    phaseB_epilogue(smem_f, t, l, nb, Bfh, Bfl, b1, W2l, W2r, g, r);
}

// layer-2 mean via CSR gather of g, +b2, +lin_r, L2-normalize, log_softmax
__global__ __launch_bounds__(256) void finalize_kernel(
    const int* __restrict__ off, const int* __restrict__ col,
    const float* __restrict__ g, const float* __restrict__ r,
    const float* __restrict__ b2,
    float* __restrict__ out)
{
    int n = blockIdx.x * 256 + threadIdx.x;
    if (n >= NN) return;
    int s0 = off[n], s1 = off[n + 1];
    float z0 = 0.0f, z1 = 0.0f, y0b = 0.0f, y1b = 0.0f;
    int i = s0;
    for (; i + 1 < s1; i += 2) {
        int sa = clampN(col[i]);
        int sb = clampN(col[i + 1]);
        float2 va = *(const float2*)(g + 2 * (size_t)sa);
        float2 vb = *(const float2*)(g + 2 * (size_t)sb);
        z0 += va.x; z1 += va.y;
        y0b += vb.x; y1b += vb.y;
    }
    if (i < s1) {
        int sa = clampN(col[i]);
        float2 va = *(const float2*)(g + 2 * (size_t)sa);
        z0 += va.x; z1 += va.y;
    }
    z0 += y0b; z1 += y1b;
    float ic = 1.0f / fmaxf((float)(s1 - s0), 1.0f);
    z0 = z0 * ic + b2[0] + r[2 * (size_t)n];
    z1 = z1 * ic + b2[1] + r[2 * (size_t)n + 1];
    float d = 1.0f / fmaxf(sqrtf(z0 * z0 + z1 * z1), FEPS);
    float y0 = z0 * d, y1 = z1 * d;
    float m = fmaxf(y0, y1);
    float lg = m + logf(__expf(y0 - m) + __expf(y1 - m));
    out[2 * (size_t)n]     = y0 - lg;
    out[2 * (size_t)n + 1] = y1 - lg;
}

// ---------------------------------------------------------------------------
extern "C" void kernel_launch(void* const* d_in, const int* in_sizes, int n_in,
                              void* d_out, int out_size, void* d_ws, size_t ws_size,
                              hipStream_t stream) {
    // setup_inputs order: x, edge_index, W1_l, b1, W1_r, W2_l, b2, W2_r
    const float* x   = (const float*)d_in[0];
    const int*   ei  = (const int*)d_in[1];
    const float* W1l = (const float*)d_in[2];
    const float* b1  = (const float*)d_in[3];
    const float* W1r = (const float*)d_in[4];
    const float* W2l = (const float*)d_in[5];
    const float* b2  = (const float*)d_in[6];
    const float* W2r = (const float*)d_in[7];

    const int nsb = (NN + 1023) / 1024;          // 98 scan blocks
    const int ncv = (NN * FIN / 8 + 255) / 256;  // convert blocks
    const int ecb = (NE + 255) / 256;            // edge blocks

    const size_t tailWords = (size_t)2 * NN + (NN + 1) + NE + 4 * NN + 128;
    const size_t needB = (size_t)256 * 256 * 4 + (size_t)NN * FIN * 2 +
                         tailWords * 4;
    const size_t needA = needB + (size_t)NN * FIN * 4;   // + agg hi/lo fp16

    // host-side constants: graph-safe
    bool pathA = (ws_size >= needA);
    bool pathB = !pathA && (ws_size >= needB);
    bool half  = pathA || pathB;

    char* p = (char*)d_ws;
    __half* Bfh = (__half*)p;             p += (size_t)256 * 256 * 2;
    __half* Bfl = (__half*)p;             p += (size_t)256 * 256 * 2;
    __half* xh = nullptr;
    if (half) { xh = (__half*)p;          p += (size_t)NN * FIN * 2; }
    __half* aggH = nullptr; __half* aggL = nullptr;
    if (pathA) {
        aggH = (__half*)p;
        aggL = aggH + (size_t)NN * 128;
        p += (size_t)NN * FIN * 4;
    }

    int*   cnt  = (int*)p;
    int*   cur  = cnt + NN;
    int*   off  = cur + NN;                      // NN+1
    int*   col  = off + NN + 1;                  // NE
    float* g    = (float*)(col + NE);            // NN*2
    float* r    = g + 2 * (size_t)NN;            // NN*2
    int*   bsum = (int*)(r + 2 * (size_t)NN);    // 128

    hipMemsetAsync(cnt, 0, 2 * (size_t)NN * sizeof(int), stream);

    int cv = half ? ncv : 0;
    setup_kernel<<<256 + cv + ecb, 256, 0, stream>>>(ei, x, W1l, W1r,
                                                     Bfh, Bfl, xh, cnt, cv);
    scan_a_kernel<<<nsb, 1024, 0, stream>>>(cnt, off, bsum);
    scan_b_kernel<<<1, 128, 0, stream>>>(bsum, off, nsb);
    scan_c_kernel<<<nsb, 1024, 0, stream>>>(bsum, off);
    fill_kernel<<<ecb, 256, 0, stream>>>(ei, off, cur, col);

    if (pathA) {
        gather_kernel<<<(NN * 16 + 255) / 256, 256, 0, stream>>>(off, col, xh,
                                                                 aggH, aggL);
        gemm_mfma_kernel<<<(NN + 63) / 64, 1024, 0, stream>>>(aggH, aggL, x,
                                                              Bfh, Bfl,
                                                              b1, W2l, W2r, g, r);
    } else if (pathB) {
        layer1_kernel<true><<<(NN + 63) / 64, 1024, 0, stream>>>(
            off, col, x, xh, Bfh, Bfl, b1, W2l, W2r, g, r);
    } else {
        layer1_kernel<false><<<(NN + 63) / 64, 1024, 0, stream>>>(
            off, col, x, xh, Bfh, Bfl, b1, W2l, W2r, g, r);
    }
    finalize_kernel<<<(NN + 255) / 256, 256, 0, stream>>>(off, col, g, r, b2,
                                                          (float*)d_out);
}

// Round 9
// 278.717 us; speedup vs baseline: 1.2707x; 1.2707x over previous
//
#include <hip/hip_runtime.h>
#include <hip/hip_fp16.h>

// Problem constants (from reference)
#define NN  100000   // nodes
#define FIN 128      // in features
#define HID 256      // hidden
#define NE  600000   // edges
#define FEPS 1e-12f

// ---------------------------------------------------------------------------
// Workspace layout (unchanged sizes):
//  Path A (~82.3 MB): Bfh|Bfl[65536]h frag-order (=256KB) | xh[NN*FIN]h |
//                     aggH|aggL[NN*128]h | cnt|cur|off|col | g|r | bsum[128]
//                     (bsum[127] doubles as the scan-completion flag)
// Evidence log:
//  - R5: bf16 FEATURES fail precision; fp16 OK (absmax 0.0156 vs thr 0.0327).
//  - R16: MFMA 3-product fp16 emulation: 245->147.8 us.
//  - R17/R20: frag-contiguous B + full unroll, bounds(512,4): 73-74 us,
//    no spill. PROVEN STRUCTURE — do not re-decompose.
//  - R19/(512,8), R21 issue-early, R22 acc[8][2]: all spilled (WRITE 20-92MB).
//  - R23 dup-1/16-wave: A-LDS duplication 4x->16x (1MB/block LDS reads,
//    conflicts 6.4M) => 166 us. Duality: B-dup costs L2, A-dup costs LDS;
//    R20's (A x4, B x2) is the measured optimum of tried points.
//  - INVARIANT (R2..R8): total = gemm + 197.4 us exactly => non-gemm pool
//    is now the bigger lever.
//  - R24 (this): (1) gemm = R20 EXACT revert; (2) scan_b+scan_c eliminated
//    (last-block pattern in scan_a scans bsum; consumers use
//    off[i]+bsum[i>>10]) => -2 launches, -1 pass; (3) gather = wave-per-node
//    (16 chunks x 4 edge-slots, shfl_xor reduce) attacking CSR latency.
//    Predicted: gemm 73-75 (VGPR~52, WRITE~1.7MB), total ~250-262,
//    absmax ~0.0156.
// ---------------------------------------------------------------------------

typedef _Float16 f16x8 __attribute__((ext_vector_type(8)));
typedef float    f32x4 __attribute__((ext_vector_type(4)));

__device__ __forceinline__ int clampN(int v) {
    return ((unsigned)v < (unsigned)NN) ? v : 0;
}
// int64 vs int32 edge_index: little-endian int64 (<2^31) => odd words all 0.
__device__ __forceinline__ int detect4(const int* ei) {
    return ((ei[1] | ei[3] | ei[5] | ei[7]) == 0) ? 1 : 0;
}
__device__ __forceinline__ int ld_src(const int* ei, int e, int f) {
    return f ? ei[2 * e] : ei[e];
}
__device__ __forceinline__ int ld_dst(const int* ei, int e, int f) {
    return f ? ei[2 * (NE + e)] : ei[NE + e];
}

__device__ __forceinline__ unsigned packh2(__half a, __half b) {
    return __builtin_bit_cast(unsigned, __halves2half2(a, b));
}

// CSR offset = per-1024-block partial scan + block base (scan_c folded away)
__device__ __forceinline__ int offAt(const int* __restrict__ off,
                                     const int* __restrict__ bsum, int i) {
    return (i < NN) ? (off[i] + bsum[i >> 10]) : NE;
}

// Fragment-order index for weight element (j, k):
// [kchunk = k>>5][jgroup = j>>4][lane = ((k>>3)&3)*16 + (j&15)][e = k&7]
__device__ __forceinline__ size_t fragIdx(int j, int k) {
    return ((size_t)((k >> 5) * 16 + (j >> 4)) * 64 +
            (size_t)(((k >> 3) & 3) * 16 + (j & 15))) * 8 + (k & 7);
}

// ---------------------------------------------------------------------------
// Setup (fused): blocks [0,256) split weights to fp16 hi/lo in FRAG layout;
// [256,256+ncv) x->fp16; [256+ncv, ...) in-degree count (cnt pre-zeroed).
// ---------------------------------------------------------------------------
__global__ __launch_bounds__(256) void setup_kernel(
    const int* __restrict__ ei,
    const float* __restrict__ x,
    const float* __restrict__ W1l, const float* __restrict__ W1r,
    __half* __restrict__ Bfh, __half* __restrict__ Bfl,
    __half* __restrict__ xh,
    int* __restrict__ cnt, int ncv)
{
    int b = blockIdx.x;
    int t = threadIdx.x;
    if (b < 256) {
        int j = b, k2 = t;   // row j of [W1l | W1r], contiguous k
        float v = (k2 < FIN) ? W1l[(size_t)j * FIN + k2]
                             : W1r[(size_t)j * FIN + (k2 - FIN)];
        __half h  = __float2half_rn(v);
        __half lo = __float2half_rn(v - __half2float(h));
        size_t fi = fragIdx(j, k2);
        Bfh[fi] = h;
        Bfl[fi] = lo;
    } else if (b < 256 + ncv) {
        int idx = (b - 256) * 256 + t;           // 8-float group
        if (idx < NN * FIN / 8) {
            const float4* px = (const float4*)(x + (size_t)idx * 8);
            float4 v0 = px[0], v1 = px[1];
            uint4 u;
            u.x = packh2(__float2half_rn(v0.x), __float2half_rn(v0.y));
            u.y = packh2(__float2half_rn(v0.z), __float2half_rn(v0.w));
            u.z = packh2(__float2half_rn(v1.x), __float2half_rn(v1.y));
            u.w = packh2(__float2half_rn(v1.z), __float2half_rn(v1.w));
            ((uint4*)xh)[idx] = u;
        }
    } else {
        int e = (b - 256 - ncv) * 256 + t;
        if (e < NE) {
            int f = detect4(ei);
            atomicAdd(cnt + clampN(ld_dst(ei, e, f)), 1);
        }
    }
}

// ---------------------------------------------------------------------------
// Fused scan: per-1024-block exclusive scan of cnt -> off (partial) + block
// totals -> bsum; the LAST block (device-scope atomic flag, G16 pattern)
// exclusive-scans bsum in place and sets off[NN]=NE sentinel slot unused
// (consumers use offAt()). Replaces scan_a+scan_b+scan_c.
// ---------------------------------------------------------------------------
__global__ __launch_bounds__(1024) void scan_kernel(
    const int* __restrict__ cnt, int* __restrict__ off, int* bsum,
    int* flag, int nblocks)
{
    __shared__ int sm[1024];
    __shared__ int amLast;
    int t = threadIdx.x;
    int idx = blockIdx.x * 1024 + t;
    int v = (idx < NN) ? cnt[idx] : 0;
    sm[t] = v;
    __syncthreads();
    for (int d = 1; d < 1024; d <<= 1) {
        int w = (t >= d) ? sm[t - d] : 0;
        __syncthreads();
        sm[t] += w;
        __syncthreads();
    }
    if (idx < NN) off[idx] = sm[t] - v;
    if (t == 1023) {
        bsum[blockIdx.x] = sm[1023];
        __threadfence();                         // device-scope: publish bsum
        amLast = (atomicAdd(flag, 1) == nblocks - 1);
    }
    __syncthreads();
    if (amLast) {
        // all other blocks' bsum writes are visible (they fenced before the
        // atomic that made us last). volatile read bypasses stale L1.
        volatile int* vb = (volatile int*)bsum;
        int bv = (t < nblocks) ? vb[t] : 0;
        __syncthreads();
        sm[t] = (t < 128) ? ((t < nblocks) ? bv : 0) : 0;
        __syncthreads();
        for (int d = 1; d < 128; d <<= 1) {
            int w2 = (t >= d && t < 128) ? sm[t - d] : 0;
            __syncthreads();
            if (t < 128) sm[t] += w2;
            __syncthreads();
        }
        if (t < nblocks) bsum[t] = sm[t] - bv;   // exclusive block base
    }
}

// place src ids into CSR slots
__global__ __launch_bounds__(256) void fill_kernel(
    const int* __restrict__ ei,
    const int* __restrict__ off, const int* __restrict__ bsum,
    int* __restrict__ cur, int* __restrict__ col)
{
    int e = blockIdx.x * 256 + threadIdx.x;
    if (e >= NE) return;
    int f = detect4(ei);
    int src = clampN(ld_src(ei, e, f));
    int dst = clampN(ld_dst(ei, e, f));
    int p = atomicAdd(cur + dst, 1);
    col[offAt(off, bsum, dst) + p] = src;
}

// ---------------------------------------------------------------------------
// Path A, stage 1: WAVE-PER-NODE gather. 64 lanes = 16 chunks x 4 edge-slots;
// edge-slot e handles edges s0+e, s0+e+4, ... (4-way cross-lane edge
// parallelism); per-chunk partials combined with shfl_xor(16/32). Mean split
// to fp16 hi/lo, written PRE-SWIZZLED (chunk ft at position ft^(n&7)) so the
// GEMM's phase-0 staging is a pure linear copy.
// ---------------------------------------------------------------------------
__global__ __launch_bounds__(256) void gather_kernel(
    const int* __restrict__ off, const int* __restrict__ bsum,
    const int* __restrict__ col,
    const __half* __restrict__ xh,
    __half* __restrict__ aggH, __half* __restrict__ aggL)
{
    int wid = (blockIdx.x * 256 + threadIdx.x) >> 6;   // global wave id = node
    if (wid >= NN) return;
    const int n     = wid;
    const int l     = threadIdx.x & 63;
    const int ft    = l & 15;
    const int e     = l >> 4;
    const int fbase = ft * 8;

    float a[8];
#pragma unroll
    for (int i = 0; i < 8; ++i) a[i] = 0.0f;

    const int s0 = offAt(off, bsum, n);
    const int s1 = offAt(off, bsum, n + 1);

    for (int i = s0 + e; i < s1; i += 4) {
        int c = clampN(col[i]);                 // 16 lanes share the address
        uint4 v = *(const uint4*)(xh + (size_t)c * FIN + fbase);
#pragma unroll
        for (int u = 0; u < 4; ++u) {
            float2 f0 = __half22float2(__builtin_bit_cast(__half2, (&v.x)[u]));
            a[2 * u]     += f0.x;
            a[2 * u + 1] += f0.y;
        }
    }
    // combine the 4 edge-slots (lanes ft, ft+16, ft+32, ft+48)
#pragma unroll
    for (int k = 0; k < 8; ++k) {
        a[k] += __shfl_xor(a[k], 16);
        a[k] += __shfl_xor(a[k], 32);
    }

    if (e == 0) {
        float ic = 1.0f / fmaxf((float)(s1 - s0), 1.0f);
        __half h[8], lo[8];
#pragma unroll
        for (int k = 0; k < 8; ++k) {
            float v = a[k] * ic;
            h[k]  = __float2half_rn(v);
            lo[k] = __float2half_rn(v - __half2float(h[k]));
        }
        uint4 uh, ul;
        uh.x = packh2(h[0], h[1]);   uh.y = packh2(h[2], h[3]);
        uh.z = packh2(h[4], h[5]);   uh.w = packh2(h[6], h[7]);
        ul.x = packh2(lo[0], lo[1]); ul.y = packh2(lo[2], lo[3]);
        ul.z = packh2(lo[4], lo[5]); ul.w = packh2(lo[6], lo[7]);
        size_t rowb = (size_t)n * 128 + (size_t)((ft ^ (n & 7)) << 3);
        *(uint4*)(aggH + rowb) = uh;
        *(uint4*)(aggL + rowb) = ul;
    }
}

// fp32 -> fp16 hi/lo split of 4 floats, stored as uint2 pairs at LDS addr.
__device__ __forceinline__ void splitStore4(
    __half* Ah, __half* Al, int addr, float4 v)
{
    __half h0 = __float2half_rn(v.x), h1 = __float2half_rn(v.y);
    __half h2 = __float2half_rn(v.z), h3 = __float2half_rn(v.w);
    __half l0 = __float2half_rn(v.x - __half2float(h0));
    __half l1 = __float2half_rn(v.y - __half2float(h1));
    __half l2 = __float2half_rn(v.z - __half2float(h2));
    __half l3 = __float2half_rn(v.w - __half2float(h3));
    uint2 uh, ul;
    uh.x = packh2(h0, h1);  uh.y = packh2(h2, h3);
    ul.x = packh2(l0, l1);  ul.y = packh2(l2, l3);
    *(uint2*)(Ah + addr) = uh;
    *(uint2*)(Al + addr) = ul;
}

// One K=128 phase: 4 kk-steps x (2 Mtiles x 4 jt) x 3 MFMAs. (R20-exact)
__device__ __forceinline__ void mfma_phase(
    const __half* Ah, const __half* Al,
    const __half* __restrict__ Bfh, const __half* __restrict__ Bfl,
    int pb /*kchunk base 0|4*/, int baseA0, int baseA1, int r7,
    int jg0, int l, f32x4 acc[2][4])
{
    const int kg = l >> 4;
#pragma unroll
    for (int kk = 0; kk < 4; ++kk) {
        const int chunk = kk * 4 + kg;          // 0..15
        const int sl = (chunk ^ r7) << 3;
        f16x8 ah0 = *reinterpret_cast<const f16x8*>(Ah + baseA0 + sl);
        f16x8 al0 = *reinterpret_cast<const f16x8*>(Al + baseA0 + sl);
        f16x8 ah1 = *reinterpret_cast<const f16x8*>(Ah + baseA1 + sl);
        f16x8 al1 = *reinterpret_cast<const f16x8*>(Al + baseA1 + sl);
#pragma unroll
        for (int jt = 0; jt < 4; ++jt) {
            const size_t bo = (((size_t)(pb + kk) * 16 + jg0 + jt) * 64 + l) * 8;
            f16x8 bh = *reinterpret_cast<const f16x8*>(Bfh + bo);
            f16x8 bl = *reinterpret_cast<const f16x8*>(Bfl + bo);
            acc[0][jt] = __builtin_amdgcn_mfma_f32_16x16x32_f16(ah0, bh, acc[0][jt], 0, 0, 0);
            acc[1][jt] = __builtin_amdgcn_mfma_f32_16x16x32_f16(ah1, bh, acc[1][jt], 0, 0, 0);
            acc[0][jt] = __builtin_amdgcn_mfma_f32_16x16x32_f16(al0, bh, acc[0][jt], 0, 0, 0);
            acc[1][jt] = __builtin_amdgcn_mfma_f32_16x16x32_f16(al1, bh, acc[1][jt], 0, 0, 0);
            acc[0][jt] = __builtin_amdgcn_mfma_f32_16x16x32_f16(ah0, bl, acc[0][jt], 0, 0, 0);
            acc[1][jt] = __builtin_amdgcn_mfma_f32_16x16x32_f16(ah1, bl, acc[1][jt], 0, 0, 0);
        }
    }
}

// ---------------------------------------------------------------------------
// Path A, stage 2: MFMA GEMM — R20 EXACT (measured 73.8/74.0 us, no spill).
// Block: 512 thr (8 waves) = 64 nodes x 256 j. LDS 32KB, K-split 2 phases.
// Wave w: nodes (w&1)*32..+31 (2 Mtiles), j-quarter (w>>1)*64 (4 jt).
// bounds(512,4): cap 128 VGPR. Do NOT tighten (R19) or re-decompose
// (R22/R23) — both regimes measured worse.
// Per tile per K-step: Ah*Bh + Al*Bh + Ah*Bl (fp32 acc) — exact emulation.
// C layout (m89-verified): col=lane&15 (j), row=(lane>>4)*4+reg (node).
// ---------------------------------------------------------------------------
__global__ __launch_bounds__(512, 4) void gemm_mfma_kernel(
    const __half* __restrict__ aggH, const __half* __restrict__ aggL,
    const float* __restrict__ x,
    const __half* __restrict__ Bfh, const __half* __restrict__ Bfl,
    const float* __restrict__ b1,
    const float* __restrict__ W2l, const float* __restrict__ W2r,
    float* __restrict__ g, float* __restrict__ r)
{
    __shared__ __half Ah[64 * 128];   // 16 KB
    __shared__ __half Al[64 * 128];   // 16 KB

    const int t  = threadIdx.x;
    const int nb = blockIdx.x * 64;

    // ---- stage phase 0: linear copy of pre-swizzled aggH/aggL ----
    {
        const uint4* gh = (const uint4*)(aggH + (size_t)nb * 128);
        const uint4* gl = (const uint4*)(aggL + (size_t)nb * 128);
#pragma unroll
        for (int i = 0; i < 2; ++i) {
            int idx = i * 512 + t;              // 0..1023 16B chunks
            *(uint4*)(Ah + idx * 8) = gh[idx];
            *(uint4*)(Al + idx * 8) = gl[idx];
        }
    }
    __syncthreads();

    const int l     = t & 63;
    const int w     = t >> 6;          // wave 0..7
    const int ln    = l & 15;
    const int kg    = l >> 4;          // 0..3
    const int mrow0 = (w & 1) * 32;    // node offset within tile
    const int jg0   = (w >> 1) * 4;    // jgroup base (j-quarter of 64)

    f32x4 acc[2][4];
#pragma unroll
    for (int mt = 0; mt < 2; ++mt)
#pragma unroll
        for (int jt = 0; jt < 4; ++jt)
            acc[mt][jt] = (f32x4){0.f, 0.f, 0.f, 0.f};

    const int rowA0  = mrow0 + ln;
    const int rowA1  = mrow0 + 16 + ln;
    const int baseA0 = rowA0 * 128;
    const int baseA1 = rowA1 * 128;
    const int r7     = ln & 7;         // (mrow0, mt*16) are 0 mod 8

    // ---- phase 0 compute (k in [0,128), kchunks 0..3) ----
    mfma_phase(Ah, Al, Bfh, Bfl, 0, baseA0, baseA1, r7, jg0, l, acc);
    __syncthreads();                    // all phase-0 LDS reads done

    // ---- stage phase 1: x fp32 -> hi/lo split, swizzled ----
    {
        const float4* xF = (const float4*)x;
        const float4 z4 = make_float4(0.f, 0.f, 0.f, 0.f);
#pragma unroll
        for (int i = 0; i < 4; ++i) {
            int idx   = i * 512 + t;        // 0..2047 = 64 rows x 32 f4
            int n_loc = idx >> 5;
            int kq    = idx & 31;
            int n     = nb + n_loc;
            float4 v  = (n < NN) ? xF[(size_t)n * 32 + kq] : z4;
            int addr  = n_loc * 128 + ((((kq >> 1) ^ (n_loc & 7)) << 3) | ((kq & 1) << 2));
            splitStore4(Ah, Al, addr, v);
        }
    }
    __syncthreads();

    // ---- phase 1 compute (k in [128,256), kchunks 4..7) ----
    mfma_phase(Ah, Al, Bfh, Bfl, 4, baseA0, baseA1, r7, jg0, l, acc);

    // ---- epilogue: per-lane partials over 4 jt, 16-lane shuffle-reduce,
    //      LDS-combine the 4 j-quarters. ----
    const int jb2 = jg0 * 16;
    float b1v[4], wl0[4], wl1[4], wr0[4], wr1[4];
#pragma unroll
    for (int jt = 0; jt < 4; ++jt) {
        int j = jb2 + jt * 16 + ln;
        b1v[jt] = b1[j];
        wl0[jt] = W2l[j];        wl1[jt] = W2l[HID + j];
        wr0[jt] = W2r[j];        wr1[jt] = W2r[HID + j];
    }

    __syncthreads();                    // phase-1 LDS reads done; overlay ok
    float* red = (float*)Ah;            // [4 jquarter][64 node][5] = 5 KB
#pragma unroll
    for (int mt = 0; mt < 2; ++mt) {
#pragma unroll
        for (int rg = 0; rg < 4; ++rg) {
            float s = 0.f, G0 = 0.f, G1 = 0.f, R0 = 0.f, R1 = 0.f;
#pragma unroll
            for (int jt = 0; jt < 4; ++jt) {
                float oo = acc[mt][jt][rg] + b1v[jt];
                s = fmaf(oo, oo, s);
                float pp = fmaxf(oo, 0.f);   // relu(o/D) = relu(o)/D
                G0 = fmaf(pp, wl0[jt], G0);
                G1 = fmaf(pp, wl1[jt], G1);
                R0 = fmaf(pp, wr0[jt], R0);
                R1 = fmaf(pp, wr1[jt], R1);
            }
#pragma unroll
            for (int m = 1; m < 16; m <<= 1) {
                s  += __shfl_xor(s, m);
                G0 += __shfl_xor(G0, m);
                G1 += __shfl_xor(G1, m);
                R0 += __shfl_xor(R0, m);
                R1 += __shfl_xor(R1, m);
            }
            if (ln == 0) {
                int n_loc = mrow0 + mt * 16 + kg * 4 + rg;
                float* pp = red + ((size_t)(w >> 1) * 64 + n_loc) * 5;
                pp[0] = s;  pp[1] = G0; pp[2] = G1; pp[3] = R0; pp[4] = R1;
            }
        }
    }
    __syncthreads();

    if (t < 64) {
        int n = nb + t;
        if (n < NN) {
            float s = 0.f, G0 = 0.f, G1 = 0.f, R0 = 0.f, R1 = 0.f;
#pragma unroll
            for (int jg = 0; jg < 4; ++jg) {
                const float* pp = red + ((size_t)jg * 64 + t) * 5;
                s += pp[0]; G0 += pp[1]; G1 += pp[2]; R0 += pp[3]; R1 += pp[4];
            }
            float inv = 1.0f / fmaxf(sqrtf(s), FEPS);
            g[2 * (size_t)n]     = G0 * inv;
            g[2 * (size_t)n + 1] = G1 * inv;
            r[2 * (size_t)n]     = R0 * inv;
            r[2 * (size_t)n + 1] = R1 * inv;
        }
    }
}

// ---------------------------------------------------------------------------
// Shared phase-B + epilogue body (FALLBACK paths only; weights reconstructed
// from fp16 hi+lo in frag layout, error ~2^-22 rel). Never runs on this
// harness (ws_size >= needA proven).
// ---------------------------------------------------------------------------
__device__ __forceinline__ void phaseB_epilogue(
    float* smem_f, int t, int l, int nb,
    const __half* __restrict__ Bfh, const __half* __restrict__ Bfl,
    const float* __restrict__ b1,
    const float* __restrict__ W2l, const float* __restrict__ W2r,
    float* __restrict__ g, float* __restrict__ r)
{
    const int w  = __builtin_amdgcn_readfirstlane(t >> 6);  // 0..15
    const int jb = w * 16;

    float o[16];
#pragma unroll
    for (int i = 0; i < 16; ++i) o[i] = 0.0f;

#pragma unroll 1
    for (int k2 = 0; k2 < 2 * FIN; k2 += 4) {
        const int nc = l ^ ((k2 >> 3) & 31);
        float av0 = smem_f[(k2 + 0) * 64 + nc];
        float av1 = smem_f[(k2 + 1) * 64 + nc];
        float av2 = smem_f[(k2 + 2) * 64 + nc];
        float av3 = smem_f[(k2 + 3) * 64 + nc];
#pragma unroll
        for (int i = 0; i < 16; ++i) {
            const size_t fb = ((size_t)((k2 >> 5) * 16 + ((jb + i) >> 4)) * 64 +
                               (size_t)(((k2 >> 3) & 3) * 16 + ((jb + i) & 15))) * 8 +
                              (k2 & 7);
            const __half* ph = Bfh + fb;
            const __half* pl = Bfl + fb;
            float oi = o[i];
            oi = fmaf(av0, __half2float(ph[0]) + __half2float(pl[0]), oi);
            oi = fmaf(av1, __half2float(ph[1]) + __half2float(pl[1]), oi);
            oi = fmaf(av2, __half2float(ph[2]) + __half2float(pl[2]), oi);
            oi = fmaf(av3, __half2float(ph[3]) + __half2float(pl[3]), oi);
            o[i] = oi;
        }
    }

    float sq = 0.f, g0 = 0.f, g1 = 0.f, r0 = 0.f, r1 = 0.f;
    const float* b1w  = b1  + jb;
    const float* w2la = W2l + jb;
    const float* w2lb = W2l + HID + jb;
    const float* w2ra = W2r + jb;
    const float* w2rb = W2r + HID + jb;
#pragma unroll
    for (int i = 0; i < 16; ++i) {
        float oo = o[i] + b1w[i];
        sq = fmaf(oo, oo, sq);
        float p = fmaxf(oo, 0.0f);
        g0 = fmaf(p, w2la[i], g0);
        g1 = fmaf(p, w2lb[i], g1);
        r0 = fmaf(p, w2ra[i], r0);
        r1 = fmaf(p, w2rb[i], r1);
    }

    __syncthreads();                          // tile dead; reuse as overlay
    smem_f[0 * 1024 + t] = sq;
    smem_f[1 * 1024 + t] = g0;
    smem_f[2 * 1024 + t] = g1;
    smem_f[3 * 1024 + t] = r0;
    smem_f[4 * 1024 + t] = r1;
    __syncthreads();

    if (t < 64) {
        int n2 = nb + t;
        float sqs = 0.f, G0 = 0.f, G1 = 0.f, R0 = 0.f, R1 = 0.f;
#pragma unroll
        for (int ww = 0; ww < 16; ++ww) {
            sqs += smem_f[0 * 1024 + ww * 64 + t];
            G0  += smem_f[1 * 1024 + ww * 64 + t];
            G1  += smem_f[2 * 1024 + ww * 64 + t];
            R0  += smem_f[3 * 1024 + ww * 64 + t];
            R1  += smem_f[4 * 1024 + ww * 64 + t];
        }
        float inv = 1.0f / fmaxf(sqrtf(sqs), FEPS);
        if (n2 < NN) {
            g[2 * (size_t)n2]     = G0 * inv;
            g[2 * (size_t)n2 + 1] = G1 * inv;
            r[2 * (size_t)n2]     = R0 * inv;
            r[2 * (size_t)n2 + 1] = R1 * inv;
        }
    }
}

// ---------------------------------------------------------------------------
// Paths B/C: fused layer-1 (B = fp16 gather, C = fp32). Fallback only.
// ---------------------------------------------------------------------------
template <bool HALFX>
__global__ __launch_bounds__(1024, 8) void layer1_kernel(
    const int* __restrict__ off, const int* __restrict__ bsum,
    const int* __restrict__ col,
    const float* __restrict__ x, const __half* __restrict__ xh,
    const __half* __restrict__ Bfh, const __half* __restrict__ Bfl,
    const float* __restrict__ b1,
    const float* __restrict__ W2l, const float* __restrict__ W2r,
    float* __restrict__ g, float* __restrict__ r)
{
    __shared__ float smem_f[256 * 64];

    const int t  = threadIdx.x;
    const int nb = blockIdx.x * 64;
    const int l  = t & 63;

    {
        const int n_loc = t >> 4;
        const int ft    = t & 15;
        const int fbase = ft * 8;
        const int n     = nb + n_loc;
        const bool valid = (n < NN);

        float a[8];
#pragma unroll
        for (int i = 0; i < 8; ++i) a[i] = 0.0f;

        int s0 = 0, s1 = 0;
        if (valid) { s0 = offAt(off, bsum, n); s1 = offAt(off, bsum, n + 1); }

        int i = s0;
        if (HALFX) {
            for (; i + 3 < s1; i += 4) {
                int c0 = clampN(col[i]);
                int c1 = clampN(col[i + 1]);
                int c2 = clampN(col[i + 2]);
                int c3 = clampN(col[i + 3]);
                uint4 v0 = *(const uint4*)(xh + (size_t)c0 * FIN + fbase);
                uint4 v1 = *(const uint4*)(xh + (size_t)c1 * FIN + fbase);
                uint4 v2 = *(const uint4*)(xh + (size_t)c2 * FIN + fbase);
                uint4 v3 = *(const uint4*)(xh + (size_t)c3 * FIN + fbase);
#pragma unroll
                for (int u = 0; u < 4; ++u) {
                    float2 f0 = __half22float2(__builtin_bit_cast(__half2, (&v0.x)[u]));
                    float2 f1 = __half22float2(__builtin_bit_cast(__half2, (&v1.x)[u]));
                    float2 f2 = __half22float2(__builtin_bit_cast(__half2, (&v2.x)[u]));
                    float2 f3 = __half22float2(__builtin_bit_cast(__half2, (&v3.x)[u]));
                    a[2 * u]     += (f0.x + f1.x) + (f2.x + f3.x);
                    a[2 * u + 1] += (f0.y + f1.y) + (f2.y + f3.y);
                }
            }
            for (; i < s1; ++i) {
                int c0 = clampN(col[i]);
                uint4 v0 = *(const uint4*)(xh + (size_t)c0 * FIN + fbase);
#pragma unroll
                for (int u = 0; u < 4; ++u) {
                    float2 f0 = __half22float2(__builtin_bit_cast(__half2, (&v0.x)[u]));
                    a[2 * u]     += f0.x;
                    a[2 * u + 1] += f0.y;
                }
            }
        } else {
            for (; i < s1; ++i) {
                int c0 = clampN(col[i]);
                const float4* p0 = (const float4*)(x + (size_t)c0 * FIN + fbase);
                float4 v00 = p0[0], v01 = p0[1];
                a[0] += v00.x; a[1] += v00.y; a[2] += v00.z; a[3] += v00.w;
                a[4] += v01.x; a[5] += v01.y; a[6] += v01.z; a[7] += v01.w;
            }
        }
        float ic = 1.0f / fmaxf((float)(s1 - s0), 1.0f);
#pragma unroll
        for (int k = 0; k < 8; ++k) {
            int f = fbase + k;
            smem_f[f * 64 + (n_loc ^ ((f >> 3) & 31))] = a[k] * ic;
        }
        const float4* sp = (const float4*)(x + (size_t)(valid ? n : 0) * FIN + fbase);
        float4 s0v = valid ? sp[0] : make_float4(0.f, 0.f, 0.f, 0.f);
        float4 s1v = valid ? sp[1] : make_float4(0.f, 0.f, 0.f, 0.f);
        float sv[8] = {s0v.x, s0v.y, s0v.z, s0v.w, s1v.x, s1v.y, s1v.z, s1v.w};
#pragma unroll
        for (int k = 0; k < 8; ++k) {
            int f = FIN + fbase + k;
            smem_f[f * 64 + (n_loc ^ ((f >> 3) & 31))] = sv[k];
        }
    }
    __syncthreads();

    phaseB_epilogue(smem_f, t, l, nb, Bfh, Bfl, b1, W2l, W2r, g, r);
}

// layer-2 mean via CSR gather of g, +b2, +lin_r, L2-normalize, log_softmax
__global__ __launch_bounds__(256) void finalize_kernel(
    const int* __restrict__ off, const int* __restrict__ bsum,
    const int* __restrict__ col,
    const float* __restrict__ g, const float* __restrict__ r,
    const float* __restrict__ b2,
    float* __restrict__ out)
{
    int n = blockIdx.x * 256 + threadIdx.x;
    if (n >= NN) return;
    int s0 = offAt(off, bsum, n), s1 = offAt(off, bsum, n + 1);
    float z0 = 0.0f, z1 = 0.0f, y0b = 0.0f, y1b = 0.0f;
    int i = s0;
    for (; i + 1 < s1; i += 2) {
        int sa = clampN(col[i]);
        int sb = clampN(col[i + 1]);
        float2 va = *(const float2*)(g + 2 * (size_t)sa);
        float2 vb = *(const float2*)(g + 2 * (size_t)sb);
        z0 += va.x; z1 += va.y;
        y0b += vb.x; y1b += vb.y;
    }
    if (i < s1) {
        int sa = clampN(col[i]);
        float2 va = *(const float2*)(g + 2 * (size_t)sa);
        z0 += va.x; z1 += va.y;
    }
    z0 += y0b; z1 += y1b;
    float ic = 1.0f / fmaxf((float)(s1 - s0), 1.0f);
    z0 = z0 * ic + b2[0] + r[2 * (size_t)n];
    z1 = z1 * ic + b2[1] + r[2 * (size_t)n + 1];
    float d = 1.0f / fmaxf(sqrtf(z0 * z0 + z1 * z1), FEPS);
    float y0 = z0 * d, y1 = z1 * d;
    float m = fmaxf(y0, y1);
    float lg = m + logf(__expf(y0 - m) + __expf(y1 - m));
    out[2 * (size_t)n]     = y0 - lg;
    out[2 * (size_t)n + 1] = y1 - lg;
}

// ---------------------------------------------------------------------------
extern "C" void kernel_launch(void* const* d_in, const int* in_sizes, int n_in,
                              void* d_out, int out_size, void* d_ws, size_t ws_size,
                              hipStream_t stream) {
    // setup_inputs order: x, edge_index, W1_l, b1, W1_r, W2_l, b2, W2_r
    const float* x   = (const float*)d_in[0];
    const int*   ei  = (const int*)d_in[1];
    const float* W1l = (const float*)d_in[2];
    const float* b1  = (const float*)d_in[3];
    const float* W1r = (const float*)d_in[4];
    const float* W2l = (const float*)d_in[5];
    const float* b2  = (const float*)d_in[6];
    const float* W2r = (const float*)d_in[7];

    const int nsb = (NN + 1023) / 1024;          // 98 scan blocks
    const int ncv = (NN * FIN / 8 + 255) / 256;  // convert blocks
    const int ecb = (NE + 255) / 256;            // edge blocks

    const size_t tailWords = (size_t)2 * NN + (NN + 1) + NE + 4 * NN + 128;
    const size_t needB = (size_t)256 * 256 * 4 + (size_t)NN * FIN * 2 +
                         tailWords * 4;
    const size_t needA = needB + (size_t)NN * FIN * 4;   // + agg hi/lo fp16

    // host-side constants: graph-safe
    bool pathA = (ws_size >= needA);
    bool pathB = !pathA && (ws_size >= needB);
    bool half  = pathA || pathB;

    char* p = (char*)d_ws;
    __half* Bfh = (__half*)p;             p += (size_t)256 * 256 * 2;
    __half* Bfl = (__half*)p;             p += (size_t)256 * 256 * 2;
    __half* xh = nullptr;
    if (half) { xh = (__half*)p;          p += (size_t)NN * FIN * 2; }
    __half* aggH = nullptr; __half* aggL = nullptr;
    if (pathA) {
        aggH = (__half*)p;
        aggL = aggH + (size_t)NN * 128;
        p += (size_t)NN * FIN * 4;
    }

    int*   cnt  = (int*)p;
    int*   cur  = cnt + NN;
    int*   off  = cur + NN;                      // NN+1
    int*   col  = off + NN + 1;                  // NE
    float* g    = (float*)(col + NE);            // NN*2
    float* r    = g + 2 * (size_t)NN;            // NN*2
    int*   bsum = (int*)(r + 2 * (size_t)NN);    // 128 (bsum[127] = flag)

    hipMemsetAsync(cnt, 0, 2 * (size_t)NN * sizeof(int), stream);
    hipMemsetAsync(bsum + 127, 0, sizeof(int), stream);   // scan flag

    int cv = half ? ncv : 0;
    setup_kernel<<<256 + cv + ecb, 256, 0, stream>>>(ei, x, W1l, W1r,
                                                     Bfh, Bfl, xh, cnt, cv);
    scan_kernel<<<nsb, 1024, 0, stream>>>(cnt, off, bsum, bsum + 127, nsb);
    fill_kernel<<<ecb, 256, 0, stream>>>(ei, off, bsum, cur, col);

    if (pathA) {
        gather_kernel<<<(NN * 64 + 255) / 256, 256, 0, stream>>>(
            off, bsum, col, xh, aggH, aggL);
        gemm_mfma_kernel<<<(NN + 63) / 64, 512, 0, stream>>>(aggH, aggL, x,
                                                             Bfh, Bfl,
                                                             b1, W2l, W2r, g, r);
    } else if (pathB) {
        layer1_kernel<true><<<(NN + 63) / 64, 1024, 0, stream>>>(
            off, bsum, col, x, xh, Bfh, Bfl, b1, W2l, W2r, g, r);
    } else {
        layer1_kernel<false><<<(NN + 63) / 64, 1024, 0, stream>>>(
            off, bsum, col, x, xh, Bfh, Bfl, b1, W2l, W2r, g, r);
    }
    finalize_kernel<<<(NN + 255) / 256, 256, 0, stream>>>(off, bsum, col, g, r,
                                                          b2, (float*)d_out);
}

// Round 10
// 271.353 us; speedup vs baseline: 1.3052x; 1.0271x over previous
//
#include <hip/hip_runtime.h>
#include <hip/hip_fp16.h>

// Problem constants (from reference)
#define NN  100000   // nodes
#define FIN 128      // in features
#define HID 256      // hidden
#define NE  600000   // edges
#define FEPS 1e-12f

// ---------------------------------------------------------------------------
// Workspace layout:
//  Path A  (~82.3 MB): Bfh|Bfl[65536]h | xh(=xHi,swizzled)[NN*128]h |
//                      aggH|aggL[NN*128]h | cnt|cur|off|col | g|r | bsum[128]
//  Path A2 (~108 MB):  + xLo[NN*128]h at the end (enables full-DMA gemm)
// Evidence log:
//  - R5: fp16 features OK (absmax 0.0156 vs thr 0.0327).
//  - R16: MFMA 3-product fp16 emulation: 245->147.8 us.
//  - R17/R20: frag-contiguous B + full unroll, bounds(512,4): 73-74 us,
//    no spill. PROVEN K-loop/decomposition — kept verbatim.
//  - R19/R21/R22: VGPR-cap/acc-size experiments all spilled (WRITE 20-92MB).
//  - R23: 16-wave dup-1 => A-LDS dup 16x, 166 us.
//  - R24: fused scan + wave-per-node gather: non-gemm pool 195.6->204.5
//    (+9us) => wave-per-node gather suspected regression (48/64 idle lanes).
//  - R25 (this): (1) gather reverted to R20 thread-per-(node,chunk) form
//    (de-confound); (2) gemm restructured single-stage K=256, 64KB LDS,
//    ALL staging via __builtin_amdgcn_global_load_lds (guide: width=16 DMA,
//    never auto-emitted; removes VGPR round-trip + staging VALU; 3 sync
//    points vs 5). x hi/lo pre-split in setup (xHi=old xh values, swizzled;
//    xLo new 25.6MB buffer) gated by pathA2 = ws>=needA2; fallback keeps
//    in-kernel split. OOB tail rows clamped on the per-lane GLOBAL address.
//    Predicted: gemm 74 -> 52-64 (A2) / 65-72 (A), VALUBusy -> 10-14%,
//    WRITE ~1.66MB, total ~250-262, absmax exactly 0.015625.
// ---------------------------------------------------------------------------

typedef _Float16 f16x8 __attribute__((ext_vector_type(8)));
typedef float    f32x4 __attribute__((ext_vector_type(4)));

__device__ __forceinline__ int clampN(int v) {
    return ((unsigned)v < (unsigned)NN) ? v : 0;
}
// int64 vs int32 edge_index: little-endian int64 (<2^31) => odd words all 0.
__device__ __forceinline__ int detect4(const int* ei) {
    return ((ei[1] | ei[3] | ei[5] | ei[7]) == 0) ? 1 : 0;
}
__device__ __forceinline__ int ld_src(const int* ei, int e, int f) {
    return f ? ei[2 * e] : ei[e];
}
__device__ __forceinline__ int ld_dst(const int* ei, int e, int f) {
    return f ? ei[2 * (NE + e)] : ei[NE + e];
}

__device__ __forceinline__ unsigned packh2(__half a, __half b) {
    return __builtin_bit_cast(unsigned, __halves2half2(a, b));
}

// CSR offset = per-1024-block partial scan + block base
__device__ __forceinline__ int offAt(const int* __restrict__ off,
                                     const int* __restrict__ bsum, int i) {
    return (i < NN) ? (off[i] + bsum[i >> 10]) : NE;
}

// async 16B global -> LDS DMA (wave-uniform LDS base + lane*16; global addr
// is per-lane). Counted by vmcnt; __syncthreads drains it.
__device__ __forceinline__ void ldsDMA16(const __half* g, __half* l) {
    __builtin_amdgcn_global_load_lds(
        (const __attribute__((address_space(1))) unsigned int*)g,
        (__attribute__((address_space(3))) unsigned int*)l, 16, 0, 0);
}

// Fragment-order index for weight element (j, k):
// [kchunk = k>>5][jgroup = j>>4][lane = ((k>>3)&3)*16 + (j&15)][e = k&7]
__device__ __forceinline__ size_t fragIdx(int j, int k) {
    return ((size_t)((k >> 5) * 16 + (j >> 4)) * 64 +
            (size_t)(((k >> 3) & 3) * 16 + (j & 15))) * 8 + (k & 7);
}

// ---------------------------------------------------------------------------
// Setup (fused): blocks [0,256) split weights to fp16 hi/lo in FRAG layout;
// [256,256+ncv) x -> xHi (swizzled; == old xh values) and xLo (if pathA2);
// [256+ncv, ...) in-degree count (cnt pre-zeroed).
// ---------------------------------------------------------------------------
__global__ __launch_bounds__(256) void setup_kernel(
    const int* __restrict__ ei,
    const float* __restrict__ x,
    const float* __restrict__ W1l, const float* __restrict__ W1r,
    __half* __restrict__ Bfh, __half* __restrict__ Bfl,
    __half* __restrict__ xh, __half* __restrict__ xLo,
    int* __restrict__ cnt, int ncv)
{
    int b = blockIdx.x;
    int t = threadIdx.x;
    if (b < 256) {
        int j = b, k2 = t;   // row j of [W1l | W1r], contiguous k
        float v = (k2 < FIN) ? W1l[(size_t)j * FIN + k2]
                             : W1r[(size_t)j * FIN + (k2 - FIN)];
        __half h  = __float2half_rn(v);
        __half lo = __float2half_rn(v - __half2float(h));
        size_t fi = fragIdx(j, k2);
        Bfh[fi] = h;
        Bfl[fi] = lo;
    } else if (b < 256 + ncv) {
        int idx = (b - 256) * 256 + t;           // 8-float group
        if (idx < NN * 16) {
            int n   = idx >> 4;
            int ftc = idx & 15;
            const float4* px = (const float4*)(x + (size_t)idx * 8);
            float4 v0 = px[0], v1 = px[1];
            float vv[8] = {v0.x, v0.y, v0.z, v0.w, v1.x, v1.y, v1.z, v1.w};
            __half h[8], lo[8];
#pragma unroll
            for (int k = 0; k < 8; ++k) {
                h[k]  = __float2half_rn(vv[k]);
                lo[k] = __float2half_rn(vv[k] - __half2float(h[k]));
            }
            uint4 uh, ul;
            uh.x = packh2(h[0], h[1]);   uh.y = packh2(h[2], h[3]);
            uh.z = packh2(h[4], h[5]);   uh.w = packh2(h[6], h[7]);
            ul.x = packh2(lo[0], lo[1]); ul.y = packh2(lo[2], lo[3]);
            ul.z = packh2(lo[4], lo[5]); ul.w = packh2(lo[6], lo[7]);
            size_t pos = (size_t)n * 128 + (size_t)((ftc ^ (n & 7)) << 3);
            *(uint4*)(xh + pos) = uh;
            if (xLo) *(uint4*)(xLo + pos) = ul;
        }
    } else {
        int e = (b - 256 - ncv) * 256 + t;
        if (e < NE) {
            int f = detect4(ei);
            atomicAdd(cnt + clampN(ld_dst(ei, e, f)), 1);
        }
    }
}

// ---------------------------------------------------------------------------
// Fused scan (R24-proven): per-block scan + last-block bsum scan (G16).
// ---------------------------------------------------------------------------
__global__ __launch_bounds__(1024) void scan_kernel(
    const int* __restrict__ cnt, int* __restrict__ off, int* bsum,
    int* flag, int nblocks)
{
    __shared__ int sm[1024];
    __shared__ int amLast;
    int t = threadIdx.x;
    int idx = blockIdx.x * 1024 + t;
    int v = (idx < NN) ? cnt[idx] : 0;
    sm[t] = v;
    __syncthreads();
    for (int d = 1; d < 1024; d <<= 1) {
        int w = (t >= d) ? sm[t - d] : 0;
        __syncthreads();
        sm[t] += w;
        __syncthreads();
    }
    if (idx < NN) off[idx] = sm[t] - v;
    if (t == 1023) {
        bsum[blockIdx.x] = sm[1023];
        __threadfence();
        amLast = (atomicAdd(flag, 1) == nblocks - 1);
    }
    __syncthreads();
    if (amLast) {
        volatile int* vb = (volatile int*)bsum;
        int bv = (t < nblocks) ? vb[t] : 0;
        __syncthreads();
        sm[t] = (t < 128) ? ((t < nblocks) ? bv : 0) : 0;
        __syncthreads();
        for (int d = 1; d < 128; d <<= 1) {
            int w2 = (t >= d && t < 128) ? sm[t - d] : 0;
            __syncthreads();
            if (t < 128) sm[t] += w2;
            __syncthreads();
        }
        if (t < nblocks) bsum[t] = sm[t] - bv;
    }
}

// place src ids into CSR slots
__global__ __launch_bounds__(256) void fill_kernel(
    const int* __restrict__ ei,
    const int* __restrict__ off, const int* __restrict__ bsum,
    int* __restrict__ cur, int* __restrict__ col)
{
    int e = blockIdx.x * 256 + threadIdx.x;
    if (e >= NE) return;
    int f = detect4(ei);
    int src = clampN(ld_src(ei, e, f));
    int dst = clampN(ld_dst(ei, e, f));
    int p = atomicAdd(cur + dst, 1);
    col[offAt(off, bsum, dst) + p] = src;
}

// ---------------------------------------------------------------------------
// Path A, stage 1: barrier-free gather — R20-PROVEN thread-per-(node,chunk)
// form (R24's wave-per-node was a +9us regression). xh rows are per-row
// swizzled by (c&7), so the chunk offset is ((ft ^ (c&7))<<3) — same VALUES
// as the old linear read. Mean split to fp16 hi/lo, written PRE-SWIZZLED.
// ---------------------------------------------------------------------------
__global__ __launch_bounds__(256) void gather_kernel(
    const int* __restrict__ off, const int* __restrict__ bsum,
    const int* __restrict__ col,
    const __half* __restrict__ xh,
    __half* __restrict__ aggH, __half* __restrict__ aggL)
{
    int idx = blockIdx.x * 256 + threadIdx.x;
    if (idx >= NN * 16) return;
    int n     = idx >> 4;
    int ft    = idx & 15;

    float a[8];
#pragma unroll
    for (int i = 0; i < 8; ++i) a[i] = 0.0f;

    int s0 = offAt(off, bsum, n), s1 = offAt(off, bsum, n + 1);
    int i = s0;
    for (; i + 3 < s1; i += 4) {            // 4 independent 16B loads
        int c0 = clampN(col[i]);
        int c1 = clampN(col[i + 1]);
        int c2 = clampN(col[i + 2]);
        int c3 = clampN(col[i + 3]);
        uint4 v0 = *(const uint4*)(xh + (size_t)c0 * FIN + ((ft ^ (c0 & 7)) << 3));
        uint4 v1 = *(const uint4*)(xh + (size_t)c1 * FIN + ((ft ^ (c1 & 7)) << 3));
        uint4 v2 = *(const uint4*)(xh + (size_t)c2 * FIN + ((ft ^ (c2 & 7)) << 3));
        uint4 v3 = *(const uint4*)(xh + (size_t)c3 * FIN + ((ft ^ (c3 & 7)) << 3));
#pragma unroll
        for (int u = 0; u < 4; ++u) {
            float2 f0 = __half22float2(__builtin_bit_cast(__half2, (&v0.x)[u]));
            float2 f1 = __half22float2(__builtin_bit_cast(__half2, (&v1.x)[u]));
            float2 f2 = __half22float2(__builtin_bit_cast(__half2, (&v2.x)[u]));
            float2 f3 = __half22float2(__builtin_bit_cast(__half2, (&v3.x)[u]));
            a[2 * u]     += (f0.x + f1.x) + (f2.x + f3.x);
            a[2 * u + 1] += (f0.y + f1.y) + (f2.y + f3.y);
        }
    }
    for (; i < s1; ++i) {
        int c0 = clampN(col[i]);
        uint4 v0 = *(const uint4*)(xh + (size_t)c0 * FIN + ((ft ^ (c0 & 7)) << 3));
#pragma unroll
        for (int u = 0; u < 4; ++u) {
            float2 f0 = __half22float2(__builtin_bit_cast(__half2, (&v0.x)[u]));
            a[2 * u]     += f0.x;
            a[2 * u + 1] += f0.y;
        }
    }
    float ic = 1.0f / fmaxf((float)(s1 - s0), 1.0f);
    __half h[8], lo[8];
#pragma unroll
    for (int k = 0; k < 8; ++k) {
        float v = a[k] * ic;
        h[k]  = __float2half_rn(v);
        lo[k] = __float2half_rn(v - __half2float(h[k]));
    }
    uint4 uh, ul;
    uh.x = packh2(h[0], h[1]);   uh.y = packh2(h[2], h[3]);
    uh.z = packh2(h[4], h[5]);   uh.w = packh2(h[6], h[7]);
    ul.x = packh2(lo[0], lo[1]); ul.y = packh2(lo[2], lo[3]);
    ul.z = packh2(lo[4], lo[5]); ul.w = packh2(lo[6], lo[7]);
    size_t rowb = (size_t)n * 128 + (size_t)((ft ^ (n & 7)) << 3);
    *(uint4*)(aggH + rowb) = uh;
    *(uint4*)(aggL + rowb) = ul;
}

// fp32 -> fp16 hi/lo split of 4 floats, stored as uint2 pairs at LDS addr.
__device__ __forceinline__ void splitStore4(
    __half* Ah, __half* Al, int addr, float4 v)
{
    __half h0 = __float2half_rn(v.x), h1 = __float2half_rn(v.y);
    __half h2 = __float2half_rn(v.z), h3 = __float2half_rn(v.w);
    __half l0 = __float2half_rn(v.x - __half2float(h0));
    __half l1 = __float2half_rn(v.y - __half2float(h1));
    __half l2 = __float2half_rn(v.z - __half2float(h2));
    __half l3 = __float2half_rn(v.w - __half2float(h3));
    uint2 uh, ul;
    uh.x = packh2(h0, h1);  uh.y = packh2(h2, h3);
    ul.x = packh2(l0, l1);  ul.y = packh2(l2, l3);
    *(uint2*)(Ah + addr) = uh;
    *(uint2*)(Al + addr) = ul;
}

// One K=128 half: 4 kk-steps x (2 Mtiles x 4 jt) x 3 MFMAs. (R20-exact)
__device__ __forceinline__ void mfma_phase(
    const __half* Ah, const __half* Al,
    const __half* __restrict__ Bfh, const __half* __restrict__ Bfl,
    int pb /*kchunk base 0|4*/, int baseA0, int baseA1, int r7,
    int jg0, int l, f32x4 acc[2][4])
{
    const int kg = l >> 4;
#pragma unroll
    for (int kk = 0; kk < 4; ++kk) {
        const int chunk = kk * 4 + kg;          // 0..15
        const int sl = (chunk ^ r7) << 3;
        f16x8 ah0 = *reinterpret_cast<const f16x8*>(Ah + baseA0 + sl);
        f16x8 al0 = *reinterpret_cast<const f16x8*>(Al + baseA0 + sl);
        f16x8 ah1 = *reinterpret_cast<const f16x8*>(Ah + baseA1 + sl);
        f16x8 al1 = *reinterpret_cast<const f16x8*>(Al + baseA1 + sl);
#pragma unroll
        for (int jt = 0; jt < 4; ++jt) {
            const size_t bo = (((size_t)(pb + kk) * 16 + jg0 + jt) * 64 + l) * 8;
            f16x8 bh = *reinterpret_cast<const f16x8*>(Bfh + bo);
            f16x8 bl = *reinterpret_cast<const f16x8*>(Bfl + bo);
            acc[0][jt] = __builtin_amdgcn_mfma_f32_16x16x32_f16(ah0, bh, acc[0][jt], 0, 0, 0);
            acc[1][jt] = __builtin_amdgcn_mfma_f32_16x16x32_f16(ah1, bh, acc[1][jt], 0, 0, 0);
            acc[0][jt] = __builtin_amdgcn_mfma_f32_16x16x32_f16(al0, bh, acc[0][jt], 0, 0, 0);
            acc[1][jt] = __builtin_amdgcn_mfma_f32_16x16x32_f16(al1, bh, acc[1][jt], 0, 0, 0);
            acc[0][jt] = __builtin_amdgcn_mfma_f32_16x16x32_f16(ah0, bl, acc[0][jt], 0, 0, 0);
            acc[1][jt] = __builtin_amdgcn_mfma_f32_16x16x32_f16(ah1, bl, acc[1][jt], 0, 0, 0);
        }
    }
}

// ---------------------------------------------------------------------------
// Path A, stage 2: MFMA GEMM — R20 K-loop/decomposition, single-stage K=256.
// LDS 64KB = AggH|AggL|XH|XL. ALL staging issued up-front; DMA=true uses
// global_load_lds for all four arrays (pre-split pre-swizzled sources);
// DMA=false uses global_load_lds for agg + in-kernel split for x.
// ONE barrier before compute (vmcnt-drained), 3 sync points total (was 5).
// Tail rows: per-lane clamp on the GLOBAL address (LDS dest stays linear).
// bounds(512,4): cap 128 VGPR (R19/R22 spill evidence — do not tighten).
// C layout (m89-verified): col=lane&15 (j), row=(lane>>4)*4+reg (node).
// ---------------------------------------------------------------------------
template <bool DMA>
__global__ __launch_bounds__(512, 4) void gemm_mfma_kernel(
    const __half* __restrict__ aggH, const __half* __restrict__ aggL,
    const float* __restrict__ x,
    const __half* __restrict__ xHi, const __half* __restrict__ xLo,
    const __half* __restrict__ Bfh, const __half* __restrict__ Bfl,
    const float* __restrict__ b1,
    const float* __restrict__ W2l, const float* __restrict__ W2r,
    float* __restrict__ g, float* __restrict__ r)
{
    __shared__ __align__(16) __half AS[4 * 64 * 128];   // 64 KB
    __half* AggHs = AS;
    __half* AggLs = AS + 64 * 128;
    __half* XHs   = AS + 2 * 64 * 128;
    __half* XLs   = AS + 3 * 64 * 128;

    const int t  = threadIdx.x;
    const int nb = blockIdx.x * 64;

    // ---- stage: issue all global->LDS DMAs up front ----
#pragma unroll
    for (int i = 0; i < 2; ++i) {
        int idx  = i * 512 + t;                  // 0..1023 16B chunks
        int row  = idx >> 4;
        int cc   = idx & 15;
        size_t srow = (size_t)clampN(nb + row) * 128 + (size_t)(cc << 3);
        ldsDMA16(aggH + srow, AggHs + (size_t)idx * 8);
        ldsDMA16(aggL + srow, AggLs + (size_t)idx * 8);
        if (DMA) {
            ldsDMA16(xHi + srow, XHs + (size_t)idx * 8);
            ldsDMA16(xLo + srow, XLs + (size_t)idx * 8);
        }
    }
    if (!DMA) {
        // in-kernel split of fp32 x (R20-exact values)
        const float4* xF = (const float4*)x;
        const float4 z4 = make_float4(0.f, 0.f, 0.f, 0.f);
#pragma unroll
        for (int i = 0; i < 4; ++i) {
            int idx   = i * 512 + t;        // 0..2047 = 64 rows x 32 f4
            int n_loc = idx >> 5;
            int kq    = idx & 31;
            int n     = nb + n_loc;
            float4 v  = (n < NN) ? xF[(size_t)n * 32 + kq] : z4;
            int addr  = n_loc * 128 + ((((kq >> 1) ^ (n_loc & 7)) << 3) | ((kq & 1) << 2));
            splitStore4(XHs, XLs, addr, v);
        }
    }
    __syncthreads();                        // drains vmcnt (DMA) + lgkm

    const int l     = t & 63;
    const int w     = t >> 6;          // wave 0..7
    const int ln    = l & 15;
    const int kg    = l >> 4;          // 0..3
    const int mrow0 = (w & 1) * 32;    // node offset within tile
    const int jg0   = (w >> 1) * 4;    // jgroup base (j-quarter of 64)

    f32x4 acc[2][4];
#pragma unroll
    for (int mt = 0; mt < 2; ++mt)
#pragma unroll
        for (int jt = 0; jt < 4; ++jt)
            acc[mt][jt] = (f32x4){0.f, 0.f, 0.f, 0.f};

    const int rowA0  = mrow0 + ln;
    const int rowA1  = mrow0 + 16 + ln;
    const int baseA0 = rowA0 * 128;
    const int baseA1 = rowA1 * 128;
    const int r7     = ln & 7;         // (mrow0, mt*16) are 0 mod 8

    // ---- K halves back-to-back (no mid barrier; disjoint LDS arrays) ----
    mfma_phase(AggHs, AggLs, Bfh, Bfl, 0, baseA0, baseA1, r7, jg0, l, acc);
    mfma_phase(XHs,   XLs,   Bfh, Bfl, 4, baseA0, baseA1, r7, jg0, l, acc);

    // ---- epilogue: per-lane partials over 4 jt, 16-lane shuffle-reduce,
    //      LDS-combine the 4 j-quarters. ----
    const int jb2 = jg0 * 16;
    float b1v[4], wl0[4], wl1[4], wr0[4], wr1[4];
#pragma unroll
    for (int jt = 0; jt < 4; ++jt) {
        int j = jb2 + jt * 16 + ln;
        b1v[jt] = b1[j];
        wl0[jt] = W2l[j];        wl1[jt] = W2l[HID + j];
        wr0[jt] = W2r[j];        wr1[jt] = W2r[HID + j];
    }

    __syncthreads();                    // LDS reads done; overlay ok
    float* red = (float*)AS;            // [4 jquarter][64 node][5] = 5 KB
#pragma unroll
    for (int mt = 0; mt < 2; ++mt) {
#pragma unroll
        for (int rg = 0; rg < 4; ++rg) {
            float s = 0.f, G0 = 0.f, G1 = 0.f, R0 = 0.f, R1 = 0.f;
#pragma unroll
            for (int jt = 0; jt < 4; ++jt) {
                float oo = acc[mt][jt][rg] + b1v[jt];
                s = fmaf(oo, oo, s);
                float pp = fmaxf(oo, 0.f);   // relu(o/D) = relu(o)/D
                G0 = fmaf(pp, wl0[jt], G0);
                G1 = fmaf(pp, wl1[jt], G1);
                R0 = fmaf(pp, wr0[jt], R0);
                R1 = fmaf(pp, wr1[jt], R1);
            }
#pragma unroll
            for (int m = 1; m < 16; m <<= 1) {
                s  += __shfl_xor(s, m);
                G0 += __shfl_xor(G0, m);
                G1 += __shfl_xor(G1, m);
                R0 += __shfl_xor(R0, m);
                R1 += __shfl_xor(R1, m);
            }
            if (ln == 0) {
                int n_loc = mrow0 + mt * 16 + kg * 4 + rg;
                float* pp = red + ((size_t)(w >> 1) * 64 + n_loc) * 5;
                pp[0] = s;  pp[1] = G0; pp[2] = G1; pp[3] = R0; pp[4] = R1;
            }
        }
    }
    __syncthreads();

    if (t < 64) {
        int n = nb + t;
        if (n < NN) {
            float s = 0.f, G0 = 0.f, G1 = 0.f, R0 = 0.f, R1 = 0.f;
#pragma unroll
            for (int jg = 0; jg < 4; ++jg) {
                const float* pp = red + ((size_t)jg * 64 + t) * 5;
                s += pp[0]; G0 += pp[1]; G1 += pp[2]; R0 += pp[3]; R1 += pp[4];
            }
            float inv = 1.0f / fmaxf(sqrtf(s), FEPS);
            g[2 * (size_t)n]     = G0 * inv;
            g[2 * (size_t)n + 1] = G1 * inv;
            r[2 * (size_t)n]     = R0 * inv;
            r[2 * (size_t)n + 1] = R1 * inv;
        }
    }
}

// ---------------------------------------------------------------------------
// Shared phase-B + epilogue body (FALLBACK paths only). Never runs on this
// harness (ws_size >= needA proven).
// ---------------------------------------------------------------------------
__device__ __forceinline__ void phaseB_epilogue(
    float* smem_f, int t, int l, int nb,
    const __half* __restrict__ Bfh, const __half* __restrict__ Bfl,
    const float* __restrict__ b1,
    const float* __restrict__ W2l, const float* __restrict__ W2r,
    float* __restrict__ g, float* __restrict__ r)
{
    const int w  = __builtin_amdgcn_readfirstlane(t >> 6);  // 0..15
    const int jb = w * 16;

    float o[16];
#pragma unroll
    for (int i = 0; i < 16; ++i) o[i] = 0.0f;

#pragma unroll 1
    for (int k2 = 0; k2 < 2 * FIN; k2 += 4) {
        const int nc = l ^ ((k2 >> 3) & 31);
        float av0 = smem_f[(k2 + 0) * 64 + nc];
        float av1 = smem_f[(k2 + 1) * 64 + nc];
        float av2 = smem_f[(k2 + 2) * 64 + nc];
        float av3 = smem_f[(k2 + 3) * 64 + nc];
#pragma unroll
        for (int i = 0; i < 16; ++i) {
            const size_t fb = ((size_t)((k2 >> 5) * 16 + ((jb + i) >> 4)) * 64 +
                               (size_t)(((k2 >> 3) & 3) * 16 + ((jb + i) & 15))) * 8 +
                              (k2 & 7);
            const __half* ph = Bfh + fb;
            const __half* pl = Bfl + fb;
            float oi = o[i];
            oi = fmaf(av0, __half2float(ph[0]) + __half2float(pl[0]), oi);
            oi = fmaf(av1, __half2float(ph[1]) + __half2float(pl[1]), oi);
            oi = fmaf(av2, __half2float(ph[2]) + __half2float(pl[2]), oi);
            oi = fmaf(av3, __half2float(ph[3]) + __half2float(pl[3]), oi);
            o[i] = oi;
        }
    }

    float sq = 0.f, g0 = 0.f, g1 = 0.f, r0 = 0.f, r1 = 0.f;
    const float* b1w  = b1  + jb;
    const float* w2la = W2l + jb;
    const float* w2lb = W2l + HID + jb;
    const float* w2ra = W2r + jb;
    const float* w2rb = W2r + HID + jb;
#pragma unroll
    for (int i = 0; i < 16; ++i) {
        float oo = o[i] + b1w[i];
        sq = fmaf(oo, oo, sq);
        float p = fmaxf(oo, 0.0f);
        g0 = fmaf(p, w2la[i], g0);
        g1 = fmaf(p, w2lb[i], g1);
        r0 = fmaf(p, w2ra[i], r0);
        r1 = fmaf(p, w2rb[i], r1);
    }

    __syncthreads();                          // tile dead; reuse as overlay
    smem_f[0 * 1024 + t] = sq;
    smem_f[1 * 1024 + t] = g0;
    smem_f[2 * 1024 + t] = g1;
    smem_f[3 * 1024 + t] = r0;
    smem_f[4 * 1024 + t] = r1;
    __syncthreads();

    if (t < 64) {
        int n2 = nb + t;
        float sqs = 0.f, G0 = 0.f, G1 = 0.f, R0 = 0.f, R1 = 0.f;
#pragma unroll
        for (int ww = 0; ww < 16; ++ww) {
            sqs += smem_f[0 * 1024 + ww * 64 + t];
            G0  += smem_f[1 * 1024 + ww * 64 + t];
            G1  += smem_f[2 * 1024 + ww * 64 + t];
            R0  += smem_f[3 * 1024 + ww * 64 + t];
            R1  += smem_f[4 * 1024 + ww * 64 + t];
        }
        float inv = 1.0f / fmaxf(sqrtf(sqs), FEPS);
        if (n2 < NN) {
            g[2 * (size_t)n2]     = G0 * inv;
            g[2 * (size_t)n2 + 1] = G1 * inv;
            r[2 * (size_t)n2]     = R0 * inv;
            r[2 * (size_t)n2 + 1] = R1 * inv;
        }
    }
}

// ---------------------------------------------------------------------------
// Paths B/C: fused layer-1 (B = fp16 gather, C = fp32). Fallback only.
// xh reads adjusted for the per-row swizzle.
// ---------------------------------------------------------------------------
template <bool HALFX>
__global__ __launch_bounds__(1024, 8) void layer1_kernel(
    const int* __restrict__ off, const int* __restrict__ bsum,
    const int* __restrict__ col,
    const float* __restrict__ x, const __half* __restrict__ xh,
    const __half* __restrict__ Bfh, const __half* __restrict__ Bfl,
    const float* __restrict__ b1,
    const float* __restrict__ W2l, const float* __restrict__ W2r,
    float* __restrict__ g, float* __restrict__ r)
{
    __shared__ float smem_f[256 * 64];

    const int t  = threadIdx.x;
    const int nb = blockIdx.x * 64;
    const int l  = t & 63;

    {
        const int n_loc = t >> 4;
        const int ft    = t & 15;
        const int fbase = ft * 8;
        const int n     = nb + n_loc;
        const bool valid = (n < NN);

        float a[8];
#pragma unroll
        for (int i = 0; i < 8; ++i) a[i] = 0.0f;

        int s0 = 0, s1 = 0;
        if (valid) { s0 = offAt(off, bsum, n); s1 = offAt(off, bsum, n + 1); }

        int i = s0;
        if (HALFX) {
            for (; i < s1; ++i) {
                int c0 = clampN(col[i]);
                uint4 v0 = *(const uint4*)(xh + (size_t)c0 * FIN + ((ft ^ (c0 & 7)) << 3));
#pragma unroll
                for (int u = 0; u < 4; ++u) {
                    float2 f0 = __half22float2(__builtin_bit_cast(__half2, (&v0.x)[u]));
                    a[2 * u]     += f0.x;
                    a[2 * u + 1] += f0.y;
                }
            }
        } else {
            for (; i < s1; ++i) {
                int c0 = clampN(col[i]);
                const float4* p0 = (const float4*)(x + (size_t)c0 * FIN + fbase);
                float4 v00 = p0[0], v01 = p0[1];
                a[0] += v00.x; a[1] += v00.y; a[2] += v00.z; a[3] += v00.w;
                a[4] += v01.x; a[5] += v01.y; a[6] += v01.z; a[7] += v01.w;
            }
        }
        float ic = 1.0f / fmaxf((float)(s1 - s0), 1.0f);
#pragma unroll
        for (int k = 0; k < 8; ++k) {
            int f = fbase + k;
            smem_f[f * 64 + (n_loc ^ ((f >> 3) & 31))] = a[k] * ic;
        }
        const float4* sp = (const float4*)(x + (size_t)(valid ? n : 0) * FIN + fbase);
        float4 s0v = valid ? sp[0] : make_float4(0.f, 0.f, 0.f, 0.f);
        float4 s1v = valid ? sp[1] : make_float4(0.f, 0.f, 0.f, 0.f);
        float sv[8] = {s0v.x, s0v.y, s0v.z, s0v.w, s1v.x, s1v.y, s1v.z, s1v.w};
#pragma unroll
        for (int k = 0; k < 8; ++k) {
            int f = FIN + fbase + k;
            smem_f[f * 64 + (n_loc ^ ((f >> 3) & 31))] = sv[k];
        }
    }
    __syncthreads();

    phaseB_epilogue(smem_f, t, l, nb, Bfh, Bfl, b1, W2l, W2r, g, r);
}

// layer-2 mean via CSR gather of g, +b2, +lin_r, L2-normalize, log_softmax
__global__ __launch_bounds__(256) void finalize_kernel(
    const int* __restrict__ off, const int* __restrict__ bsum,
    const int* __restrict__ col,
    const float* __restrict__ g, const float* __restrict__ r,
    const float* __restrict__ b2,
    float* __restrict__ out)
{
    int n = blockIdx.x * 256 + threadIdx.x;
    if (n >= NN) return;
    int s0 = offAt(off, bsum, n), s1 = offAt(off, bsum, n + 1);
    float z0 = 0.0f, z1 = 0.0f, y0b = 0.0f, y1b = 0.0f;
    int i = s0;
    for (; i + 1 < s1; i += 2) {
        int sa = clampN(col[i]);
        int sb = clampN(col[i + 1]);
        float2 va = *(const float2*)(g + 2 * (size_t)sa);
        float2 vb = *(const float2*)(g + 2 * (size_t)sb);
        z0 += va.x; z1 += va.y;
        y0b += vb.x; y1b += vb.y;
    }
    if (i < s1) {
        int sa = clampN(col[i]);
        float2 va = *(const float2*)(g + 2 * (size_t)sa);
        z0 += va.x; z1 += va.y;
    }
    z0 += y0b; z1 += y1b;
    float ic = 1.0f / fmaxf((float)(s1 - s0), 1.0f);
    z0 = z0 * ic + b2[0] + r[2 * (size_t)n];
    z1 = z1 * ic + b2[1] + r[2 * (size_t)n + 1];
    float d = 1.0f / fmaxf(sqrtf(z0 * z0 + z1 * z1), FEPS);
    float y0 = z0 * d, y1 = z1 * d;
    float m = fmaxf(y0, y1);
    float lg = m + logf(__expf(y0 - m) + __expf(y1 - m));
    out[2 * (size_t)n]     = y0 - lg;
    out[2 * (size_t)n + 1] = y1 - lg;
}

// ---------------------------------------------------------------------------
extern "C" void kernel_launch(void* const* d_in, const int* in_sizes, int n_in,
                              void* d_out, int out_size, void* d_ws, size_t ws_size,
                              hipStream_t stream) {
    // setup_inputs order: x, edge_index, W1_l, b1, W1_r, W2_l, b2, W2_r
    const float* x   = (const float*)d_in[0];
    const int*   ei  = (const int*)d_in[1];
    const float* W1l = (const float*)d_in[2];
    const float* b1  = (const float*)d_in[3];
    const float* W1r = (const float*)d_in[4];
    const float* W2l = (const float*)d_in[5];
    const float* b2  = (const float*)d_in[6];
    const float* W2r = (const float*)d_in[7];

    const int nsb = (NN + 1023) / 1024;          // 98 scan blocks
    const int ncv = (NN * FIN / 8 + 255) / 256;  // convert blocks
    const int ecb = (NE + 255) / 256;            // edge blocks

    const size_t tailWords = (size_t)2 * NN + (NN + 1) + NE + 4 * NN + 128;
    const size_t needB = (size_t)256 * 256 * 4 + (size_t)NN * FIN * 2 +
                         tailWords * 4;
    const size_t needA  = needB + (size_t)NN * FIN * 4;   // + agg hi/lo fp16
    const size_t needA2 = needA + (size_t)NN * FIN * 2;   // + xLo

    // host-side constants: graph-safe
    bool pathA2 = (ws_size >= needA2);
    bool pathA  = (ws_size >= needA);
    bool pathB  = !pathA && (ws_size >= needB);
    bool half   = pathA || pathB;

    char* p = (char*)d_ws;
    __half* Bfh = (__half*)p;             p += (size_t)256 * 256 * 2;
    __half* Bfl = (__half*)p;             p += (size_t)256 * 256 * 2;
    __half* xh = nullptr;
    if (half) { xh = (__half*)p;          p += (size_t)NN * FIN * 2; }
    __half* aggH = nullptr; __half* aggL = nullptr;
    if (pathA) {
        aggH = (__half*)p;
        aggL = aggH + (size_t)NN * 128;
        p += (size_t)NN * FIN * 4;
    }

    int*   cnt  = (int*)p;
    int*   cur  = cnt + NN;
    int*   off  = cur + NN;                      // NN+1
    int*   col  = off + NN + 1;                  // NE
    float* g    = (float*)(col + NE);            // NN*2
    float* r    = g + 2 * (size_t)NN;            // NN*2
    int*   bsum = (int*)(r + 2 * (size_t)NN);    // 128 (bsum[127] = flag)
    __half* xLo = pathA2 ? (__half*)(bsum + 128) : nullptr;   // NN*128

    hipMemsetAsync(cnt, 0, 2 * (size_t)NN * sizeof(int), stream);
    hipMemsetAsync(bsum + 127, 0, sizeof(int), stream);   // scan flag

    int cv = half ? ncv : 0;
    setup_kernel<<<256 + cv + ecb, 256, 0, stream>>>(ei, x, W1l, W1r,
                                                     Bfh, Bfl, xh, xLo,
                                                     cnt, cv);
    scan_kernel<<<nsb, 1024, 0, stream>>>(cnt, off, bsum, bsum + 127, nsb);
    fill_kernel<<<ecb, 256, 0, stream>>>(ei, off, bsum, cur, col);

    if (pathA) {
        gather_kernel<<<(NN * 16 + 255) / 256, 256, 0, stream>>>(
            off, bsum, col, xh, aggH, aggL);
        if (pathA2) {
            gemm_mfma_kernel<true><<<(NN + 63) / 64, 512, 0, stream>>>(
                aggH, aggL, x, xh, xLo, Bfh, Bfl, b1, W2l, W2r, g, r);
        } else {
            gemm_mfma_kernel<false><<<(NN + 63) / 64, 512, 0, stream>>>(
                aggH, aggL, x, xh, xLo, Bfh, Bfl, b1, W2l, W2r, g, r);
        }
    } else if (pathB) {
        layer1_kernel<true><<<(NN + 63) / 64, 1024, 0, stream>>>(
            off, bsum, col, x, xh, Bfh, Bfl, b1, W2l, W2r, g, r);
    } else {
        layer1_kernel<false><<<(NN + 63) / 64, 1024, 0, stream>>>(
            off, bsum, col, x, xh, Bfh, Bfl, b1, W2l, W2r, g, r);
    }
    finalize_kernel<<<(NN + 255) / 256, 256, 0, stream>>>(off, bsum, col, g, r,
                                                          b2, (float*)d_out);
}